// Round 1
// baseline (1432.089 us; speedup 1.0000x reference)
//
#include <hip/hip_runtime.h>
#include <hip/hip_bf16.h>
#include <math.h>

// Problem constants (StructureGuidedAttention: B=4, S=1024, D=1024, H=16, dk=64, G=7)
#define BB 4
#define SS 1024
#define DD 1024
#define NH 16
#define DK 64
#define GD 7

// ---------------------------------------------------------------------------
// Generic 64x64-tile fp32 GEMM: C[M=4096][N=1024] = A @ W + bias
// mode 0..2: scatter output to head-major [B][H][S][DK]  (QKV projections)
// mode 3:    plain row-major [M][N]                      (out projection)
// ---------------------------------------------------------------------------
__global__ __launch_bounds__(256) void gemm64(const float* __restrict__ A,
                                              const float* __restrict__ W,
                                              const float* __restrict__ bias,
                                              float* __restrict__ out,
                                              int mode) {
  __shared__ float As[16][68];  // As[k][m], pad 68 keeps 16B align + kills store conflicts
  __shared__ float Bs[16][64];  // Bs[k][n]
  const int t = threadIdx.x;
  const int m0 = blockIdx.x * 64;
  const int n0 = blockIdx.y * 64;
  const int tm = t >> 4, tn = t & 15;
  float acc[4][4] = {{0.f}};

  for (int k0 = 0; k0 < DD; k0 += 16) {
    {  // A tile: 64 rows x 16 k, transposed into As[k][m]
      const int row = t >> 2;            // 0..63
      const int kc = (t & 3) * 4;        // 0,4,8,12
      const float4 a4 = *(const float4*)(A + (size_t)(m0 + row) * DD + k0 + kc);
      As[kc + 0][row] = a4.x;
      As[kc + 1][row] = a4.y;
      As[kc + 2][row] = a4.z;
      As[kc + 3][row] = a4.w;
    }
    {  // B tile: 16 k x 64 n
      const int row = t >> 4;            // 0..15
      const int nc = (t & 15) * 4;       // 0..60
      *(float4*)&Bs[row][nc] = *(const float4*)(W + (size_t)(k0 + row) * DD + n0 + nc);
    }
    __syncthreads();
#pragma unroll
    for (int kk = 0; kk < 16; ++kk) {
      const float4 av = *(const float4*)&As[kk][tm * 4];
      const float4 bv = *(const float4*)&Bs[kk][tn * 4];
      const float a[4] = {av.x, av.y, av.z, av.w};
      const float b[4] = {bv.x, bv.y, bv.z, bv.w};
#pragma unroll
      for (int i = 0; i < 4; ++i)
#pragma unroll
        for (int j = 0; j < 4; ++j) acc[i][j] = fmaf(a[i], b[j], acc[i][j]);
    }
    __syncthreads();
  }

#pragma unroll
  for (int i = 0; i < 4; ++i) {
    const int m = m0 + tm * 4 + i;
#pragma unroll
    for (int j = 0; j < 4; ++j) {
      const int n = n0 + tn * 4 + j;
      const float v = acc[i][j] + bias[n];
      if (mode < 3) {
        const int b = m >> 10, s = m & 1023;
        const int h = n >> 6, d = n & 63;
        out[(((size_t)(b * NH + h)) * SS + s) * DK + d] = v;
      } else {
        out[(size_t)m * DD + n] = v;
      }
    }
  }
}

// ---------------------------------------------------------------------------
// Fused attention: per block = (head h, q-tile of 16, batch b).
// 4 waves, each wave owns 4 q rows. Loop over 16 chunks of 64 keys:
//   stage K-chunk and V-chunk^T into LDS (XOR-swizzled float4 layout),
//   scores = QK^T/8 + geom-bias, mask, online softmax, PV accumulate.
// Never materializes the S x S score matrix.
// ---------------------------------------------------------------------------
__global__ __launch_bounds__(256) void attn(const float* __restrict__ Q,
                                            const float* __restrict__ K,
                                            const float* __restrict__ V,
                                            const float* __restrict__ geom,
                                            const int* __restrict__ mask,
                                            const float* __restrict__ Wg,
                                            const float* __restrict__ bg,
                                            float* __restrict__ ctxbuf) {
  // element [j][c4] lives at [j][c4 ^ (j&15)] (float4 units) -> conflict-free b128
  __shared__ float4 Ks4[64 * 16];  // K chunk:   Ks[j][d]      (64 keys x 64 dims)
  __shared__ float4 Vt4[64 * 16];  // V chunk^T: Vt[d][j]      (64 dims x 64 keys)
  __shared__ float4 qs4[16 * 16];  // 16 q rows x 64 dims
  __shared__ float4 ps4[16 * 16];  // p values: [w*4+r][64 keys]

  const int t = threadIdx.x;
  const int w = t >> 6;        // wave 0..3
  const int lane = t & 63;
  const int h = blockIdx.x, qt = blockIdx.y, b = blockIdx.z;
  const size_t bh = (size_t)b * NH + h;
  const float* Qb = Q + bh * SS * DK;
  const float* Kb = K + bh * SS * DK;
  const float* Vb = V + bh * SS * DK;
  const int q0 = qt * 16;
  float* psf = (float*)ps4;

  {  // stage the 16 q rows (one float4 per thread, coalesced)
    const int row = t >> 4, c = t & 15;
    qs4[row * 16 + c] = *(const float4*)(Qb + (size_t)(q0 + row) * DK + c * 4);
  }

  float wgv[GD];
#pragma unroll
  for (int g = 0; g < GD; ++g) wgv[g] = Wg[g * NH + h];
  const float bgh = bg[h];

  float m_i[4], l_i[4], ctx[4];
#pragma unroll
  for (int r = 0; r < 4; ++r) {
    m_i[r] = -INFINITY;
    l_i[r] = 0.f;
    ctx[r] = 0.f;
  }
  const int qrow0 = q0 + w * 4;

  for (int c = 0; c < 16; ++c) {
    const int k0 = c * 64;
    __syncthreads();  // prev-chunk LDS consumers done (also covers qs staging at c==0)

    // ---- stage K chunk (swizzled) ----
#pragma unroll
    for (int i = 0; i < 4; ++i) {
      const int u = t + i * 256;
      const int row = u >> 4, cc = u & 15;
      Ks4[row * 16 + (cc ^ (row & 15))] =
          *(const float4*)(Kb + (size_t)(k0 + row) * DK + cc * 4);
    }
    // ---- stage V chunk transposed (swizzled) ----
#pragma unroll
    for (int i = 0; i < 4; ++i) {
      const int u = t + i * 256;
      const int j = u >> 4, d4 = u & 15;
      const float4 vv = *(const float4*)(Vb + (size_t)(k0 + j) * DK + d4 * 4);
      float* vt = (float*)Vt4;
      const int jc = j >> 2, jel = j & 3;
      int d;
      d = d4 * 4 + 0; vt[d * 64 + ((jc ^ (d & 15)) * 4) + jel] = vv.x;
      d = d4 * 4 + 1; vt[d * 64 + ((jc ^ (d & 15)) * 4) + jel] = vv.y;
      d = d4 * 4 + 2; vt[d * 64 + ((jc ^ (d & 15)) * 4) + jel] = vv.z;
      d = d4 * 4 + 3; vt[d * 64 + ((jc ^ (d & 15)) * 4) + jel] = vv.w;
    }
    __syncthreads();

    // ---- QK^T: lane = key j ----
    float s[4] = {0.f, 0.f, 0.f, 0.f};
#pragma unroll
    for (int c4 = 0; c4 < 16; ++c4) {
      const float4 kv = Ks4[lane * 16 + (c4 ^ (lane & 15))];
#pragma unroll
      for (int r = 0; r < 4; ++r) {
        const float4 qv = qs4[(w * 4 + r) * 16 + c4];  // wave-uniform broadcast
        s[r] += kv.x * qv.x + kv.y * qv.y + kv.z * qv.z + kv.w * qv.w;
      }
    }

    // ---- geometric bias + mask ----
    const int kk = k0 + lane;
    const int mk = mask[b * SS + kk];
#pragma unroll
    for (int r = 0; r < 4; ++r) {
      const float* gp = geom + (((size_t)b * SS + (qrow0 + r)) * SS + kk) * GD;
      float bi = bgh;
#pragma unroll
      for (int g = 0; g < GD; ++g) bi = fmaf(gp[g], wgv[g], bi);
      s[r] = s[r] * 0.125f + bi;      // scale = 1/sqrt(64)
      if (mk == 0) s[r] = -10000.f;   // mask REPLACES the score (matches reference)
    }

    // ---- online softmax (per wave, per q-row) ----
    float p[4];
#pragma unroll
    for (int r = 0; r < 4; ++r) {
      float cm = s[r];
#pragma unroll
      for (int off = 32; off > 0; off >>= 1) cm = fmaxf(cm, __shfl_xor(cm, off, 64));
      const float mn = fmaxf(m_i[r], cm);
      const float alpha = __expf(m_i[r] - mn);  // exp(-inf)=0 on first chunk
      p[r] = __expf(s[r] - mn);
      float sp = p[r];
#pragma unroll
      for (int off = 32; off > 0; off >>= 1) sp += __shfl_xor(sp, off, 64);
      l_i[r] = l_i[r] * alpha + sp;
      m_i[r] = mn;
      ctx[r] *= alpha;                // lane acts as dim d for the accumulator
      psf[(w * 4 + r) * 64 + lane] = p[r];
    }
    __syncthreads();  // ps visible (block-wide barrier; uniform control flow)

    // ---- PV: lane = dim d ----
#pragma unroll
    for (int j4 = 0; j4 < 16; ++j4) {
      const float4 vv = Vt4[lane * 16 + (j4 ^ (lane & 15))];
#pragma unroll
      for (int r = 0; r < 4; ++r) {
        const float4 pv = ps4[(w * 4 + r) * 16 + j4];  // wave-uniform broadcast
        ctx[r] += pv.x * vv.x + pv.y * vv.y + pv.z * vv.z + pv.w * vv.w;
      }
    }
  }

  // ---- write ctx back in [B][S][D] layout for the out-projection ----
#pragma unroll
  for (int r = 0; r < 4; ++r) {
    const float inv = 1.f / l_i[r];
    ctxbuf[((size_t)b * SS + (qrow0 + r)) * DD + h * DK + lane] = ctx[r] * inv;
  }
}

// ---------------------------------------------------------------------------
extern "C" void kernel_launch(void* const* d_in, const int* in_sizes, int n_in,
                              void* d_out, int out_size, void* d_ws, size_t ws_size,
                              hipStream_t stream) {
  const float* x    = (const float*)d_in[0];
  const float* geom = (const float*)d_in[1];
  const int*   mask = (const int*)d_in[2];
  const float* Wq   = (const float*)d_in[3];
  const float* bq   = (const float*)d_in[4];
  const float* Wk   = (const float*)d_in[5];
  const float* bk   = (const float*)d_in[6];
  const float* Wv   = (const float*)d_in[7];
  const float* bv   = (const float*)d_in[8];
  const float* Wo   = (const float*)d_in[9];
  const float* bo   = (const float*)d_in[10];
  const float* Wg   = (const float*)d_in[11];
  const float* bg   = (const float*)d_in[12];
  float* out = (float*)d_out;

  // workspace: Q, K, V in [B][H][S][DK], ctx in [B][S][D] — 4 x 16 MiB fp32
  const size_t NEL = (size_t)BB * SS * DD;  // 4,194,304
  float* Qb = (float*)d_ws;
  float* Kb = Qb + NEL;
  float* Vb = Kb + NEL;
  float* Cb = Vb + NEL;

  const dim3 gg(64, 16), blk(256);
  gemm64<<<gg, blk, 0, stream>>>(x, Wq, bq, Qb, 0);
  gemm64<<<gg, blk, 0, stream>>>(x, Wk, bk, Kb, 1);
  gemm64<<<gg, blk, 0, stream>>>(x, Wv, bv, Vb, 2);
  attn<<<dim3(NH, SS / 16, BB), blk, 0, stream>>>(Qb, Kb, Vb, geom, mask, Wg, bg, Cb);
  gemm64<<<gg, blk, 0, stream>>>(Cb, Wo, bo, out, 3);
}

// Round 2
// 1378.065 us; speedup vs baseline: 1.0392x; 1.0392x over previous
//
#include <hip/hip_runtime.h>
#include <hip/hip_bf16.h>
#include <math.h>

// Problem constants (StructureGuidedAttention: B=4, S=1024, D=1024, H=16, dk=64, G=7)
#define BB 4
#define SS 1024
#define DD 1024
#define NH 16
#define DK 64
#define GD 7

// ---------------------------------------------------------------------------
// Generic 64x64-tile fp32 GEMM: C[M=4096][N=1024] = A @ W + bias
// mode 0..2: scatter output to head-major [B][H][S][DK]  (QKV projections)
// mode 3:    plain row-major [M][N]                      (out projection)
// ---------------------------------------------------------------------------
__global__ __launch_bounds__(256) void gemm64(const float* __restrict__ A,
                                              const float* __restrict__ W,
                                              const float* __restrict__ bias,
                                              float* __restrict__ out,
                                              int mode) {
  __shared__ float As[16][68];  // As[k][m], pad 68 keeps 16B align + kills store conflicts
  __shared__ float Bs[16][64];  // Bs[k][n]
  const int t = threadIdx.x;
  const int m0 = blockIdx.x * 64;
  const int n0 = blockIdx.y * 64;
  const int tm = t >> 4, tn = t & 15;
  float acc[4][4] = {{0.f}};

  for (int k0 = 0; k0 < DD; k0 += 16) {
    {  // A tile: 64 rows x 16 k, transposed into As[k][m]
      const int row = t >> 2;            // 0..63
      const int kc = (t & 3) * 4;        // 0,4,8,12
      const float4 a4 = *(const float4*)(A + (size_t)(m0 + row) * DD + k0 + kc);
      As[kc + 0][row] = a4.x;
      As[kc + 1][row] = a4.y;
      As[kc + 2][row] = a4.z;
      As[kc + 3][row] = a4.w;
    }
    {  // B tile: 16 k x 64 n
      const int row = t >> 4;            // 0..15
      const int nc = (t & 15) * 4;       // 0..60
      *(float4*)&Bs[row][nc] = *(const float4*)(W + (size_t)(k0 + row) * DD + n0 + nc);
    }
    __syncthreads();
#pragma unroll
    for (int kk = 0; kk < 16; ++kk) {
      const float4 av = *(const float4*)&As[kk][tm * 4];
      const float4 bv = *(const float4*)&Bs[kk][tn * 4];
      const float a[4] = {av.x, av.y, av.z, av.w};
      const float b[4] = {bv.x, bv.y, bv.z, bv.w};
#pragma unroll
      for (int i = 0; i < 4; ++i)
#pragma unroll
        for (int j = 0; j < 4; ++j) acc[i][j] = fmaf(a[i], b[j], acc[i][j]);
    }
    __syncthreads();
  }

#pragma unroll
  for (int i = 0; i < 4; ++i) {
    const int m = m0 + tm * 4 + i;
#pragma unroll
    for (int j = 0; j < 4; ++j) {
      const int n = n0 + tn * 4 + j;
      const float v = acc[i][j] + bias[n];
      if (mode < 3) {
        const int b = m >> 10, s = m & 1023;
        const int h = n >> 6, d = n & 63;
        out[(((size_t)(b * NH + h)) * SS + s) * DK + d] = v;
      } else {
        out[(size_t)m * DD + n] = v;
      }
    }
  }
}

// ---------------------------------------------------------------------------
// Fused attention: per block = (head h, q-tile of 16, batch b).
// 4 waves, each wave owns 4 q rows. Loop over 16 chunks of 64 keys:
//   stage K-chunk and V-chunk^T into LDS (XOR-swizzled float4 layout),
//   cooperative vectorized geom-bias into LDS (thread = (q-row, key-group)),
//   p = exp(QK/8 + bias)*mask  (no max-subtraction: |score| <~ 2.5 analytically),
//   per-lane l accumulation (one reduction at the very end), PV accumulate.
// Never materializes the S x S score matrix.
// ---------------------------------------------------------------------------
__global__ __launch_bounds__(256) void attn(const float* __restrict__ Q,
                                            const float* __restrict__ K,
                                            const float* __restrict__ V,
                                            const float* __restrict__ geom,
                                            const int* __restrict__ mask,
                                            const float* __restrict__ Wg,
                                            const float* __restrict__ bg,
                                            float* __restrict__ ctxbuf) {
  // element [j][c4] lives at [j][c4 ^ (j&15)] (float4 units) -> conflict-free b128
  __shared__ float4 Ks4[64 * 16];   // K chunk:   Ks[j][d]      (64 keys x 64 dims)
  __shared__ float4 Vt4[64 * 16];   // V chunk^T: Vt[d][j]      (64 dims x 64 keys)
  __shared__ float4 qs4[16 * 16];   // 16 q rows x 64 dims
  __shared__ float4 ps4[16 * 16];   // p values: [w*4+r][64 keys]
  __shared__ float biasLDS[16 * 64];  // struct bias for this chunk [q row][key]

  const int t = threadIdx.x;
  const int w = t >> 6;        // wave 0..3
  const int lane = t & 63;
  const int h = blockIdx.x, qt = blockIdx.y, b = blockIdx.z;
  const size_t bh = (size_t)b * NH + h;
  const float* Qb = Q + bh * SS * DK;
  const float* Kb = K + bh * SS * DK;
  const float* Vb = V + bh * SS * DK;
  const int q0 = qt * 16;
  float* psf = (float*)ps4;

  {  // stage the 16 q rows (one float4 per thread, coalesced)
    const int row = t >> 4, c = t & 15;
    qs4[row * 16 + c] = *(const float4*)(Qb + (size_t)(q0 + row) * DK + c * 4);
  }

  float wgv[GD];
#pragma unroll
  for (int g = 0; g < GD; ++g) wgv[g] = Wg[g * NH + h];
  const float bgh = bg[h];

  // geom base for this thread: q row gq = t>>4, key group gk = (t&15)*4.
  // Per chunk the thread reads 28 contiguous floats (4 keys x 7) = 7 float4,
  // then advances by 64 keys (= 448 floats).
  const int gq = t >> 4;
  const int gk = (t & 15) * 4;
  const float* gptr = geom + (((size_t)b * SS + (q0 + gq)) * SS + gk) * GD;

  float lsum[4] = {0.f, 0.f, 0.f, 0.f};
  float ctx[4] = {0.f, 0.f, 0.f, 0.f};
  const int qrow0 = q0 + w * 4;

  for (int c = 0; c < 16; ++c) {
    const int k0 = c * 64;
    __syncthreads();  // prev-chunk LDS consumers done (also covers qs staging at c==0)

    // ---- stage K chunk (swizzled) ----
#pragma unroll
    for (int i = 0; i < 4; ++i) {
      const int u = t + i * 256;
      const int row = u >> 4, cc = u & 15;
      Ks4[row * 16 + (cc ^ (row & 15))] =
          *(const float4*)(Kb + (size_t)(k0 + row) * DK + cc * 4);
    }
    // ---- stage V chunk transposed (swizzled) ----
#pragma unroll
    for (int i = 0; i < 4; ++i) {
      const int u = t + i * 256;
      const int j = u >> 4, d4 = u & 15;
      const float4 vv = *(const float4*)(Vb + (size_t)(k0 + j) * DK + d4 * 4);
      float* vt = (float*)Vt4;
      const int jc = j >> 2, jel = j & 3;
      int d;
      d = d4 * 4 + 0; vt[d * 64 + ((jc ^ (d & 15)) * 4) + jel] = vv.x;
      d = d4 * 4 + 1; vt[d * 64 + ((jc ^ (d & 15)) * 4) + jel] = vv.y;
      d = d4 * 4 + 2; vt[d * 64 + ((jc ^ (d & 15)) * 4) + jel] = vv.z;
      d = d4 * 4 + 3; vt[d * 64 + ((jc ^ (d & 15)) * 4) + jel] = vv.w;
    }

    // ---- cooperative geom bias: 7 float4 loads + 28 fma + 1 float4 LDS write
    {
      float4 gv[7];
#pragma unroll
      for (int j = 0; j < 7; ++j) gv[j] = *(const float4*)(gptr + j * 4);
      gptr += 64 * GD;
      const float* gf = (const float*)gv;  // 28 floats = 4 keys x 7 features
      float4 bvv;
      float* bvf = &bvv.x;
#pragma unroll
      for (int k2 = 0; k2 < 4; ++k2) {
        float bi = bgh;
#pragma unroll
        for (int g = 0; g < GD; ++g) bi = fmaf(gf[k2 * GD + g], wgv[g], bi);
        bvf[k2] = bi;
      }
      *(float4*)&biasLDS[gq * 64 + gk] = bvv;
    }
    __syncthreads();

    // ---- QK^T: lane = key j ----
    float s[4] = {0.f, 0.f, 0.f, 0.f};
#pragma unroll
    for (int c4 = 0; c4 < 16; ++c4) {
      const float4 kv = Ks4[lane * 16 + (c4 ^ (lane & 15))];
#pragma unroll
      for (int r = 0; r < 4; ++r) {
        const float4 qv = qs4[(w * 4 + r) * 16 + c4];  // wave-uniform broadcast
        s[r] += kv.x * qv.x + kv.y * qv.y + kv.z * qv.z + kv.w * qv.w;
      }
    }

    // ---- p = exp(s/8 + bias) * mask; defer l reduction to the end ----
    const float mskf = (mask[b * SS + k0 + lane] != 0) ? 1.f : 0.f;
#pragma unroll
    for (int r = 0; r < 4; ++r) {
      const float p = __expf(fmaf(s[r], 0.125f, biasLDS[(w * 4 + r) * 64 + lane])) * mskf;
      lsum[r] += p;
      psf[(w * 4 + r) * 64 + lane] = p;
    }
    __syncthreads();  // ps visible to all waves (uniform control flow)

    // ---- PV: lane = dim d ----
#pragma unroll
    for (int j4 = 0; j4 < 16; ++j4) {
      const float4 vv = Vt4[lane * 16 + (j4 ^ (lane & 15))];
#pragma unroll
      for (int r = 0; r < 4; ++r) {
        const float4 pv = ps4[(w * 4 + r) * 16 + j4];  // wave-uniform broadcast
        ctx[r] += pv.x * vv.x + pv.y * vv.y + pv.z * vv.z + pv.w * vv.w;
      }
    }
  }

  // ---- final: reduce l across the 64 key-lanes, then normalize & store ----
#pragma unroll
  for (int r = 0; r < 4; ++r) {
    float l = lsum[r];
#pragma unroll
    for (int off = 32; off > 0; off >>= 1) l += __shfl_xor(l, off, 64);
    const float inv = 1.f / l;
    ctxbuf[((size_t)b * SS + (qrow0 + r)) * DD + h * DK + lane] = ctx[r] * inv;
  }
}

// ---------------------------------------------------------------------------
extern "C" void kernel_launch(void* const* d_in, const int* in_sizes, int n_in,
                              void* d_out, int out_size, void* d_ws, size_t ws_size,
                              hipStream_t stream) {
  const float* x    = (const float*)d_in[0];
  const float* geom = (const float*)d_in[1];
  const int*   mask = (const int*)d_in[2];
  const float* Wq   = (const float*)d_in[3];
  const float* bq   = (const float*)d_in[4];
  const float* Wk   = (const float*)d_in[5];
  const float* bk   = (const float*)d_in[6];
  const float* Wv   = (const float*)d_in[7];
  const float* bv   = (const float*)d_in[8];
  const float* Wo   = (const float*)d_in[9];
  const float* bo   = (const float*)d_in[10];
  const float* Wg   = (const float*)d_in[11];
  const float* bg   = (const float*)d_in[12];
  float* out = (float*)d_out;

  // workspace: Q, K, V in [B][H][S][DK], ctx in [B][S][D] — 4 x 16 MiB fp32
  const size_t NEL = (size_t)BB * SS * DD;  // 4,194,304
  float* Qb = (float*)d_ws;
  float* Kb = Qb + NEL;
  float* Vb = Kb + NEL;
  float* Cb = Vb + NEL;

  const dim3 gg(64, 16), blk(256);
  gemm64<<<gg, blk, 0, stream>>>(x, Wq, bq, Qb, 0);
  gemm64<<<gg, blk, 0, stream>>>(x, Wk, bk, Kb, 1);
  gemm64<<<gg, blk, 0, stream>>>(x, Wv, bv, Vb, 2);
  attn<<<dim3(NH, SS / 16, BB), blk, 0, stream>>>(Qb, Kb, Vb, geom, mask, Wg, bg, Cb);
  gemm64<<<gg, blk, 0, stream>>>(Cb, Wo, bo, out, 3);
}

// Round 3
// 957.726 us; speedup vs baseline: 1.4953x; 1.4389x over previous
//
#include <hip/hip_runtime.h>
#include <hip/hip_bf16.h>
#include <math.h>

// Problem constants (StructureGuidedAttention: B=4, S=1024, D=1024, H=16, dk=64, G=7)
#define BB 4
#define SS 1024
#define DD 1024
#define NH 16
#define DK 64
#define GD 7

typedef _Float16 half8 __attribute__((ext_vector_type(8)));
typedef _Float16 half4v __attribute__((ext_vector_type(4)));
typedef float floatx4 __attribute__((ext_vector_type(4)));

// ---------------------------------------------------------------------------
// Generic 64x64-tile fp32 GEMM: C[M=4096][N=1024] = A @ W + bias
// mode 0..2: scatter output to head-major [B][H][S][DK]  (QKV projections)
// mode 3:    plain row-major [M][N]                      (out projection)
// ---------------------------------------------------------------------------
__global__ __launch_bounds__(256) void gemm64(const float* __restrict__ A,
                                              const float* __restrict__ W,
                                              const float* __restrict__ bias,
                                              float* __restrict__ out,
                                              int mode) {
  __shared__ float As[16][68];
  __shared__ float Bs[16][64];
  const int t = threadIdx.x;
  const int m0 = blockIdx.x * 64;
  const int n0 = blockIdx.y * 64;
  const int tm = t >> 4, tn = t & 15;
  float acc[4][4] = {{0.f}};

  for (int k0 = 0; k0 < DD; k0 += 16) {
    {
      const int row = t >> 2;
      const int kc = (t & 3) * 4;
      const float4 a4 = *(const float4*)(A + (size_t)(m0 + row) * DD + k0 + kc);
      As[kc + 0][row] = a4.x;
      As[kc + 1][row] = a4.y;
      As[kc + 2][row] = a4.z;
      As[kc + 3][row] = a4.w;
    }
    {
      const int row = t >> 4;
      const int nc = (t & 15) * 4;
      *(float4*)&Bs[row][nc] = *(const float4*)(W + (size_t)(k0 + row) * DD + n0 + nc);
    }
    __syncthreads();
#pragma unroll
    for (int kk = 0; kk < 16; ++kk) {
      const float4 av = *(const float4*)&As[kk][tm * 4];
      const float4 bv = *(const float4*)&Bs[kk][tn * 4];
      const float a[4] = {av.x, av.y, av.z, av.w};
      const float b[4] = {bv.x, bv.y, bv.z, bv.w};
#pragma unroll
      for (int i = 0; i < 4; ++i)
#pragma unroll
        for (int j = 0; j < 4; ++j) acc[i][j] = fmaf(a[i], b[j], acc[i][j]);
    }
    __syncthreads();
  }

#pragma unroll
  for (int i = 0; i < 4; ++i) {
    const int m = m0 + tm * 4 + i;
#pragma unroll
    for (int j = 0; j < 4; ++j) {
      const int n = n0 + tn * 4 + j;
      const float v = acc[i][j] + bias[n];
      if (mode < 3) {
        const int b = m >> 10, s = m & 1023;
        const int h = n >> 6, d = n & 63;
        out[(((size_t)(b * NH + h)) * SS + s) * DK + d] = v;
      } else {
        out[(size_t)m * DD + n] = v;
      }
    }
  }
}

// ---------------------------------------------------------------------------
// MFMA flash attention. Block = (head h, 64 q-rows, batch b); 4 waves x 16 q.
// Per 64-key chunk: stage K (f16, half8 XOR-swizzle), V^T (f16, pad-72),
// bias (fp32, pad-68) in LDS; QK^T via mfma_f32_16x16x32_f16 (Q frags
// hoisted in registers); p = exp(s/8+bias)*mask (no max-subtraction —
// scores bounded); P round-trips C-layout -> LDS -> A-layout; PV via MFMA.
// ---------------------------------------------------------------------------
__global__ __launch_bounds__(256) void attn(const float* __restrict__ Q,
                                            const float* __restrict__ K,
                                            const float* __restrict__ V,
                                            const float* __restrict__ geom,
                                            const int* __restrict__ mask,
                                            const float* __restrict__ Wg,
                                            const float* __restrict__ bg,
                                            float* __restrict__ ctxbuf) {
  __shared__ _Float16 Ks[64 * 64];      // K chunk [key][8 half8-units, XOR-swizzled]; Q staging pre-loop
  __shared__ _Float16 Vt[64 * 72];      // V^T chunk [dim][key], row pitch 72
  __shared__ float biasL[64 * 68];      // struct bias [q][key], row pitch 68
  __shared__ _Float16 pL[4 * 16 * 72];  // per-wave P [16 q][key], pitch 72
  __shared__ float maskf[SS];           // mask row as float

  const int t = threadIdx.x;
  const int w = t >> 6, lane = t & 63;
  const int quad = lane >> 4, col = lane & 15;
  const int h = blockIdx.x, qt = blockIdx.y, b = blockIdx.z;
  const int q0 = qt * 64;
  const size_t bh = (size_t)b * NH + h;
  const float* Qb = Q + bh * SS * DK;
  const float* Kb = K + bh * SS * DK;
  const float* Vb = V + bh * SS * DK;

  // ---- mask -> LDS as float multiplier (1024 entries, 4 per thread) ----
  {
    const int4 m4 = *(const int4*)(mask + b * SS + t * 4);
    float4 f4;
    f4.x = m4.x ? 1.f : 0.f;
    f4.y = m4.y ? 1.f : 0.f;
    f4.z = m4.z ? 1.f : 0.f;
    f4.w = m4.w ? 1.f : 0.f;
    *(float4*)&maskf[t * 4] = f4;
  }

  float wgv[GD];
#pragma unroll
  for (int g = 0; g < GD; ++g) wgv[g] = Wg[g * NH + h];
  const float bgh = bg[h];

  // ---- stage Q tile (64 q x 64 d) into Ks buffer (f16, swizzled), grab frags ----
  {
    const int j = t >> 2, u2 = (t & 3) * 2;  // row j, half8-units u2,u2+1
    float4 f[4];
#pragma unroll
    for (int e = 0; e < 4; ++e)
      f[e] = *(const float4*)(Qb + (size_t)(q0 + j) * DK + u2 * 8 + e * 4);
    half8 h0, h1;
    h0[0] = (_Float16)f[0].x; h0[1] = (_Float16)f[0].y;
    h0[2] = (_Float16)f[0].z; h0[3] = (_Float16)f[0].w;
    h0[4] = (_Float16)f[1].x; h0[5] = (_Float16)f[1].y;
    h0[6] = (_Float16)f[1].z; h0[7] = (_Float16)f[1].w;
    h1[0] = (_Float16)f[2].x; h1[1] = (_Float16)f[2].y;
    h1[2] = (_Float16)f[2].z; h1[3] = (_Float16)f[2].w;
    h1[4] = (_Float16)f[3].x; h1[5] = (_Float16)f[3].y;
    h1[6] = (_Float16)f[3].z; h1[7] = (_Float16)f[3].w;
    *(half8*)&Ks[(j * 8 + (u2 ^ (j & 7))) * 8] = h0;
    *(half8*)&Ks[(j * 8 + ((u2 + 1) ^ (j & 7))) * 8] = h1;
  }
  __syncthreads();
  half8 qfrag[2];
  {
    const int qrow = w * 16 + col;  // A-frag: m = lane&15
#pragma unroll
    for (int kk = 0; kk < 2; ++kk) {
      const int u = quad + kk * 4;  // k-range = quad*8 + kk*32
      qfrag[kk] = *(const half8*)&Ks[(qrow * 8 + (u ^ (qrow & 7))) * 8];
    }
  }

  const floatx4 zero4 = {0.f, 0.f, 0.f, 0.f};
  floatx4 ctx[4] = {zero4, zero4, zero4, zero4};
  float lsum[4] = {0.f, 0.f, 0.f, 0.f};
  const int gq = t >> 2;           // bias: this thread's q row (0..63)
  const int gk = (t & 3) * 16;     // bias: first of 16 keys
  const float* gptr = geom + (((size_t)b * SS + (q0 + gq)) * SS + gk) * GD;
  _Float16* pW = &pL[w * 16 * 72];

  for (int c = 0; c < 16; ++c) {
    const int k0 = c * 64;
    __syncthreads();  // prev-chunk consumers done (also protects Q-frag reads at c==0)

    // ---- stage K chunk: f16, half8 XOR-swizzled ----
    {
      const int j = t >> 2, u2 = (t & 3) * 2;
      float4 f[4];
#pragma unroll
      for (int e = 0; e < 4; ++e)
        f[e] = *(const float4*)(Kb + (size_t)(k0 + j) * DK + u2 * 8 + e * 4);
      half8 h0, h1;
      h0[0] = (_Float16)f[0].x; h0[1] = (_Float16)f[0].y;
      h0[2] = (_Float16)f[0].z; h0[3] = (_Float16)f[0].w;
      h0[4] = (_Float16)f[1].x; h0[5] = (_Float16)f[1].y;
      h0[6] = (_Float16)f[1].z; h0[7] = (_Float16)f[1].w;
      h1[0] = (_Float16)f[2].x; h1[1] = (_Float16)f[2].y;
      h1[2] = (_Float16)f[2].z; h1[3] = (_Float16)f[2].w;
      h1[4] = (_Float16)f[3].x; h1[5] = (_Float16)f[3].y;
      h1[6] = (_Float16)f[3].z; h1[7] = (_Float16)f[3].w;
      *(half8*)&Ks[(j * 8 + (u2 ^ (j & 7))) * 8] = h0;
      *(half8*)&Ks[(j * 8 + ((u2 + 1) ^ (j & 7))) * 8] = h1;
    }

    // ---- stage V^T chunk: 4x4 register-tile transpose, b64 writes ----
    {
      const int key4 = (t >> 4) * 4, d4 = (t & 15) * 4;
      float4 f[4];
#pragma unroll
      for (int e = 0; e < 4; ++e)
        f[e] = *(const float4*)(Vb + (size_t)(k0 + key4 + e) * DK + d4);
      const float* ff = (const float*)f;
#pragma unroll
      for (int i = 0; i < 4; ++i) {
        half4v hv;
        hv[0] = (_Float16)ff[0 * 4 + i];
        hv[1] = (_Float16)ff[1 * 4 + i];
        hv[2] = (_Float16)ff[2 * 4 + i];
        hv[3] = (_Float16)ff[3 * 4 + i];
        *(half4v*)&Vt[(d4 + i) * 72 + key4] = hv;
      }
    }

    // ---- cooperative geom bias: thread = (q row, 16 keys) ----
    {
#pragma unroll
      for (int sg = 0; sg < 4; ++sg) {  // 4 keys per subgroup
        float4 gv[7];
#pragma unroll
        for (int i = 0; i < 7; ++i) gv[i] = *(const float4*)(gptr + sg * 28 + i * 4);
        const float* gf = (const float*)gv;
        float4 bv;
        float* bvf = &bv.x;
#pragma unroll
        for (int k2 = 0; k2 < 4; ++k2) {
          float bi = bgh;
#pragma unroll
          for (int g = 0; g < GD; ++g) bi = fmaf(gf[k2 * GD + g], wgv[g], bi);
          bvf[k2] = bi;
        }
        *(float4*)&biasL[gq * 68 + gk + sg * 4] = bv;
      }
      gptr += 64 * GD;
    }
    __syncthreads();  // staging visible

    // ---- QK^T: 8 MFMAs -> scores in C-layout [q=quad*4+reg][key=nt*16+col] ----
    floatx4 sc[4] = {zero4, zero4, zero4, zero4};
#pragma unroll
    for (int nt = 0; nt < 4; ++nt) {
      const int key = nt * 16 + col;  // B-frag: n = lane&15
#pragma unroll
      for (int kk = 0; kk < 2; ++kk) {
        const int u = quad + kk * 4;
        const half8 kf = *(const half8*)&Ks[(key * 8 + (u ^ (key & 7))) * 8];
        sc[nt] = __builtin_amdgcn_mfma_f32_16x16x32_f16(qfrag[kk], kf, sc[nt], 0, 0, 0);
      }
    }

    // ---- scale + bias + mask + exp; write P (f16) to per-wave LDS ----
#pragma unroll
    for (int nt = 0; nt < 4; ++nt) {
      const float mv = maskf[k0 + nt * 16 + col];
#pragma unroll
      for (int reg = 0; reg < 4; ++reg) {
        const int q = quad * 4 + reg;
        const float s = fmaf(sc[nt][reg], 0.125f, biasL[(w * 16 + q) * 68 + nt * 16 + col]);
        const float p = __expf(s) * mv;
        lsum[reg] += p;
        pW[q * 72 + nt * 16 + col] = (_Float16)p;
      }
    }
    // (same-wave LDS RAW: compiler inserts lgkmcnt wait; lanes run in lockstep)

    // ---- PV: 8 MFMAs, accumulate ctx in C-layout [q][dim=nt*16+col] ----
#pragma unroll
    for (int kk = 0; kk < 2; ++kk) {
      const half8 pa = *(const half8*)&pW[col * 72 + quad * 8 + kk * 32];
#pragma unroll
      for (int nt = 0; nt < 4; ++nt) {
        const half8 vb = *(const half8*)&Vt[(nt * 16 + col) * 72 + quad * 8 + kk * 32];
        ctx[nt] = __builtin_amdgcn_mfma_f32_16x16x32_f16(pa, vb, ctx[nt], 0, 0, 0);
      }
    }
  }

  // ---- reduce l across the 16 cols (key-lanes) within each quad ----
  float inv[4];
#pragma unroll
  for (int reg = 0; reg < 4; ++reg) {
    float l = lsum[reg];
    l += __shfl_xor(l, 1, 64);
    l += __shfl_xor(l, 2, 64);
    l += __shfl_xor(l, 4, 64);
    l += __shfl_xor(l, 8, 64);
    inv[reg] = 1.f / l;
  }

  // ---- store ctx [B][S][D] fp32 for the out-projection ----
#pragma unroll
  for (int nt = 0; nt < 4; ++nt) {
#pragma unroll
    for (int reg = 0; reg < 4; ++reg) {
      const int q = q0 + w * 16 + quad * 4 + reg;
      ctxbuf[((size_t)b * SS + q) * DD + h * DK + nt * 16 + col] = ctx[nt][reg] * inv[reg];
    }
  }
}

// ---------------------------------------------------------------------------
extern "C" void kernel_launch(void* const* d_in, const int* in_sizes, int n_in,
                              void* d_out, int out_size, void* d_ws, size_t ws_size,
                              hipStream_t stream) {
  const float* x    = (const float*)d_in[0];
  const float* geom = (const float*)d_in[1];
  const int*   mask = (const int*)d_in[2];
  const float* Wq   = (const float*)d_in[3];
  const float* bq   = (const float*)d_in[4];
  const float* Wk   = (const float*)d_in[5];
  const float* bk   = (const float*)d_in[6];
  const float* Wv   = (const float*)d_in[7];
  const float* bv   = (const float*)d_in[8];
  const float* Wo   = (const float*)d_in[9];
  const float* bo   = (const float*)d_in[10];
  const float* Wg   = (const float*)d_in[11];
  const float* bg   = (const float*)d_in[12];
  float* out = (float*)d_out;

  const size_t NEL = (size_t)BB * SS * DD;
  float* Qb = (float*)d_ws;
  float* Kb = Qb + NEL;
  float* Vb = Kb + NEL;
  float* Cb = Vb + NEL;

  const dim3 gg(64, 16), blk(256);
  gemm64<<<gg, blk, 0, stream>>>(x, Wq, bq, Qb, 0);
  gemm64<<<gg, blk, 0, stream>>>(x, Wk, bk, Kb, 1);
  gemm64<<<gg, blk, 0, stream>>>(x, Wv, bv, Vb, 2);
  attn<<<dim3(NH, SS / 64, BB), blk, 0, stream>>>(Qb, Kb, Vb, geom, mask, Wg, bg, Cb);
  gemm64<<<gg, blk, 0, stream>>>(Cb, Wo, bo, out, 3);
}

// Round 4
// 619.810 us; speedup vs baseline: 2.3105x; 1.5452x over previous
//
#include <hip/hip_runtime.h>
#include <hip/hip_bf16.h>
#include <math.h>

// Problem constants (StructureGuidedAttention: B=4, S=1024, D=1024, H=16, dk=64, G=7)
#define BB 4
#define SS 1024
#define DD 1024
#define NH 16
#define DK 64
#define GD 7

typedef _Float16 half8 __attribute__((ext_vector_type(8)));
typedef _Float16 half4v __attribute__((ext_vector_type(4)));
typedef float floatx4 __attribute__((ext_vector_type(4)));

__device__ inline half8 cvt8(const float4 a, const float4 b) {
  half8 h;
  h[0] = (_Float16)a.x; h[1] = (_Float16)a.y; h[2] = (_Float16)a.z; h[3] = (_Float16)a.w;
  h[4] = (_Float16)b.x; h[5] = (_Float16)b.y; h[6] = (_Float16)b.z; h[7] = (_Float16)b.w;
  return h;
}

// ---------------------------------------------------------------------------
// x (fp32, 4M elements) -> f16
// ---------------------------------------------------------------------------
__global__ __launch_bounds__(256) void cvtx(const float* __restrict__ x,
                                            _Float16* __restrict__ xh) {
  const int i = blockIdx.x * 256 + threadIdx.x;
  const float4 a = ((const float4*)x)[i * 2];
  const float4 b = ((const float4*)x)[i * 2 + 1];
  ((half8*)xh)[i] = cvt8(a, b);
}

// ---------------------------------------------------------------------------
// Pack Wq|Wk|Wv|Wo (each [1024 k][1024 n] fp32) transposed into
// Wt[which][n][k] f16.  64x64 LDS tile transpose per block.
// ---------------------------------------------------------------------------
__global__ __launch_bounds__(256) void packw(const float* __restrict__ Wq,
                                             const float* __restrict__ Wk,
                                             const float* __restrict__ Wv,
                                             const float* __restrict__ Wo,
                                             _Float16* __restrict__ Wt) {
  __shared__ _Float16 Tl[64 * 72];  // [n][k] pitch 72 (16B-aligned rows)
  const int t = threadIdx.x;
  const int k0 = blockIdx.x * 64, n0 = blockIdx.y * 64, z = blockIdx.z;
  const float* src = (z == 0) ? Wq : (z == 1) ? Wk : (z == 2) ? Wv : Wo;
#pragma unroll
  for (int i = 0; i < 4; ++i) {
    const int u = i * 256 + t;
    const int r = u >> 4, c4 = (u & 15) * 4;  // k row r, n cols c4..c4+3
    const float4 v = *(const float4*)(src + (size_t)(k0 + r) * DD + n0 + c4);
    Tl[(c4 + 0) * 72 + r] = (_Float16)v.x;
    Tl[(c4 + 1) * 72 + r] = (_Float16)v.y;
    Tl[(c4 + 2) * 72 + r] = (_Float16)v.z;
    Tl[(c4 + 3) * 72 + r] = (_Float16)v.w;
  }
  __syncthreads();
  _Float16* dst = Wt + (size_t)z * DD * DD;
#pragma unroll
  for (int i = 0; i < 2; ++i) {
    const int u = i * 256 + t;
    const int nr = u >> 3, ks = u & 7;
    const half8 hv = *(const half8*)&Tl[nr * 72 + ks * 8];
    *(half8*)(dst + (size_t)(n0 + nr) * DD + k0 + ks * 8) = hv;
  }
}

// ---------------------------------------------------------------------------
// bias16[b][h][q][k] (f16) = geom[b,q,k,:] @ Wg[:,h] + bg[h]; -100 if masked.
// One block per (q, b): stage the 28KB geom row once, reuse for all 16 heads.
// ---------------------------------------------------------------------------
__global__ __launch_bounds__(256) void biasprep(const float* __restrict__ geom,
                                                const int* __restrict__ mask,
                                                const float* __restrict__ Wg,
                                                const float* __restrict__ bg,
                                                _Float16* __restrict__ bias16) {
  __shared__ float geomL[SS * GD];      // 28 KB
  __shared__ unsigned char mskL[SS];
  const int t = threadIdx.x;
  const int q = blockIdx.x, b = blockIdx.y;
  const float* gr = geom + ((size_t)b * SS + q) * SS * GD;
#pragma unroll
  for (int i = 0; i < 7; ++i) {
    const int u = i * 256 + t;
    *(float4*)&geomL[u * 4] = *(const float4*)(gr + u * 4);
  }
  {
    const int4 m4 = *(const int4*)(mask + b * SS + t * 4);
    mskL[t * 4 + 0] = m4.x != 0;
    mskL[t * 4 + 1] = m4.y != 0;
    mskL[t * 4 + 2] = m4.z != 0;
    mskL[t * 4 + 3] = m4.w != 0;
  }
  __syncthreads();
  const int h = t >> 4, kk0 = (t & 15) * 64;
  float wgv[GD];
#pragma unroll
  for (int g = 0; g < GD; ++g) wgv[g] = Wg[g * NH + h];
  const float bgh = bg[h];
  _Float16* dst = bias16 + (((size_t)b * NH + h) * SS + q) * SS + kk0;
#pragma unroll
  for (int c8 = 0; c8 < 8; ++c8) {
    half8 hv;
#pragma unroll
    for (int e = 0; e < 8; ++e) {
      const int k = kk0 + c8 * 8 + e;
      float bi = bgh;
#pragma unroll
      for (int g = 0; g < GD; ++g) bi = fmaf(geomL[k * GD + g], wgv[g], bi);
      hv[e] = mskL[k] ? (_Float16)bi : (_Float16)(-100.f);
    }
    *(half8*)(dst + c8 * 8) = hv;
  }
}

// ---------------------------------------------------------------------------
// f16 MFMA GEMM, 128x128 tile, BK=64, 4 waves in 2x2.
// MODE 0: C[4096][3072] = xh @ Wt(qkv)^T + b  -> scatter f16 head-major Q/K/V
// MODE 1: C[4096][1024] = ctxh @ Wt(o)^T + bo -> fp32 row-major d_out
// ---------------------------------------------------------------------------
template <int MODE>
__global__ __launch_bounds__(256) void hgemm(const _Float16* __restrict__ A,
                                             const _Float16* __restrict__ Bt,
                                             const float* __restrict__ b0,
                                             const float* __restrict__ b1,
                                             const float* __restrict__ b2,
                                             _Float16* __restrict__ Oq,
                                             _Float16* __restrict__ Ok,
                                             _Float16* __restrict__ Ov,
                                             float* __restrict__ Of) {
  __shared__ _Float16 Als[128 * 72];  // [m][k] rows of 64 f16, pitch 72
  __shared__ _Float16 Bls[128 * 72];  // [n][k]
  const int t = threadIdx.x;
  const int w = t >> 6, lane = t & 63, quad = lane >> 4, col = lane & 15;
  const int m0 = blockIdx.x * 128, n0 = blockIdx.y * 128;
  const int mw = (w >> 1) * 64, nw = (w & 1) * 64;
  const floatx4 zero4 = {0.f, 0.f, 0.f, 0.f};
  floatx4 acc[4][4];
#pragma unroll
  for (int i = 0; i < 4; ++i)
#pragma unroll
    for (int j = 0; j < 4; ++j) acc[i][j] = zero4;

  for (int k0 = 0; k0 < DD; k0 += 64) {
#pragma unroll
    for (int i = 0; i < 4; ++i) {  // A tile: 128 rows x 8 f16x8-units
      const int u = i * 256 + t;
      const int row = u >> 3, seg = u & 7;
      const half8 hv = *(const half8*)(A + (size_t)(m0 + row) * DD + k0 + seg * 8);
      *(half8*)&Als[row * 72 + seg * 8] = hv;
    }
#pragma unroll
    for (int i = 0; i < 4; ++i) {  // B tile
      const int u = i * 256 + t;
      const int row = u >> 3, seg = u & 7;
      const half8 hv = *(const half8*)(Bt + (size_t)(n0 + row) * DD + k0 + seg * 8);
      *(half8*)&Bls[row * 72 + seg * 8] = hv;
    }
    __syncthreads();
#pragma unroll
    for (int kk = 0; kk < 2; ++kk) {
      half8 af[4], bf[4];
      const int u = (quad + kk * 4) * 8;
#pragma unroll
      for (int i = 0; i < 4; ++i) af[i] = *(const half8*)&Als[(mw + i * 16 + col) * 72 + u];
#pragma unroll
      for (int j = 0; j < 4; ++j) bf[j] = *(const half8*)&Bls[(nw + j * 16 + col) * 72 + u];
#pragma unroll
      for (int i = 0; i < 4; ++i)
#pragma unroll
        for (int j = 0; j < 4; ++j)
          acc[i][j] = __builtin_amdgcn_mfma_f32_16x16x32_f16(af[i], bf[j], acc[i][j], 0, 0, 0);
    }
    __syncthreads();
  }

#pragma unroll
  for (int j = 0; j < 4; ++j) {
    const int n = n0 + nw + j * 16 + col;
    if (MODE == 0) {
      const int which = n >> 10, hd = n & 1023;
      const int h = hd >> 6, d = hd & 63;
      const float* bp = (which == 0) ? b0 : (which == 1) ? b1 : b2;
      const float bias = bp[hd];
      _Float16* ob = (which == 0) ? Oq : (which == 1) ? Ok : Ov;
#pragma unroll
      for (int i = 0; i < 4; ++i) {
#pragma unroll
        for (int reg = 0; reg < 4; ++reg) {
          const int m = m0 + mw + i * 16 + quad * 4 + reg;
          const int b = m >> 10, s = m & 1023;
          ob[(((size_t)b * NH + h) * SS + s) * DK + d] = (_Float16)(acc[i][j][reg] + bias);
        }
      }
    } else {
      const float bias = b0[n];
#pragma unroll
      for (int i = 0; i < 4; ++i) {
#pragma unroll
        for (int reg = 0; reg < 4; ++reg) {
          const int m = m0 + mw + i * 16 + quad * 4 + reg;
          Of[(size_t)m * DD + n] = acc[i][j][reg] + bias;
        }
      }
    }
  }
}

// ---------------------------------------------------------------------------
// MFMA flash attention, f16 Q/K/V inputs, f16 ctx output.
// PREBIAS: bias read from precomputed bias16 (mask folded as -100).
// !PREBIAS: geom bias computed inline (fallback when ws is small).
// ---------------------------------------------------------------------------
template <bool PREBIAS>
__global__ __launch_bounds__(256) void attn(const _Float16* __restrict__ Q,
                                            const _Float16* __restrict__ K,
                                            const _Float16* __restrict__ V,
                                            const _Float16* __restrict__ bias16,
                                            const float* __restrict__ geom,
                                            const int* __restrict__ mask,
                                            const float* __restrict__ Wg,
                                            const float* __restrict__ bg,
                                            _Float16* __restrict__ ctxbuf) {
  __shared__ _Float16 Ks[64 * 64];      // K chunk, half8 XOR-swizzled (Q staging pre-loop)
  __shared__ _Float16 Vt[64 * 72];      // V^T chunk [dim][key], pitch 72
  __shared__ _Float16 biasL[64 * 72];   // bias chunk [q][key], pitch 72
  __shared__ _Float16 pL[4 * 16 * 72];  // per-wave P [16 q][key], pitch 72
  __shared__ unsigned char mskL[SS];    // fallback only

  const int t = threadIdx.x;
  const int w = t >> 6, lane = t & 63, quad = lane >> 4, col = lane & 15;
  const int h = blockIdx.x, qt = blockIdx.y, b = blockIdx.z;
  const int q0 = qt * 64;
  const size_t bh = (size_t)b * NH + h;
  const _Float16* Qb = Q + bh * SS * DK;
  const _Float16* Kb = K + bh * SS * DK;
  const _Float16* Vb = V + bh * SS * DK;

  {  // stage Q tile (64 q x 64 d) into Ks, swizzled
    const int j = t >> 2, u2 = (t & 3) * 2;
    const half8 h0 = *(const half8*)(Qb + (size_t)(q0 + j) * DK + u2 * 8);
    const half8 h1 = *(const half8*)(Qb + (size_t)(q0 + j) * DK + u2 * 8 + 8);
    *(half8*)&Ks[(j * 8 + (u2 ^ (j & 7))) * 8] = h0;
    *(half8*)&Ks[(j * 8 + ((u2 + 1) ^ (j & 7))) * 8] = h1;
  }
  if constexpr (!PREBIAS) {
    const int4 m4 = *(const int4*)(mask + b * SS + t * 4);
    mskL[t * 4 + 0] = m4.x != 0;
    mskL[t * 4 + 1] = m4.y != 0;
    mskL[t * 4 + 2] = m4.z != 0;
    mskL[t * 4 + 3] = m4.w != 0;
  }
  __syncthreads();
  half8 qfrag[2];
  {
    const int qrow = w * 16 + col;
#pragma unroll
    for (int kk = 0; kk < 2; ++kk) {
      const int u = quad + kk * 4;
      qfrag[kk] = *(const half8*)&Ks[(qrow * 8 + (u ^ (qrow & 7))) * 8];
    }
  }

  float wgv[GD];
  float bgh = 0.f;
  const float* gptr = nullptr;
  if constexpr (!PREBIAS) {
#pragma unroll
    for (int g = 0; g < GD; ++g) wgv[g] = Wg[g * NH + h];
    bgh = bg[h];
    gptr = geom + (((size_t)b * SS + (q0 + (t >> 2))) * SS + (t & 3) * 16) * GD;
  }
  const _Float16* bbase = nullptr;
  if constexpr (PREBIAS) bbase = bias16 + (bh * SS + q0) * SS;

  const floatx4 zero4 = {0.f, 0.f, 0.f, 0.f};
  floatx4 ctx[4] = {zero4, zero4, zero4, zero4};
  float lsum[4] = {0.f, 0.f, 0.f, 0.f};
  _Float16* pW = &pL[w * 16 * 72];

  for (int c = 0; c < 16; ++c) {
    const int k0 = c * 64;
    __syncthreads();  // prev-chunk consumers done (also protects qfrag at c==0)

    {  // K chunk, swizzled
      const int j = t >> 2, u2 = (t & 3) * 2;
      const half8 h0 = *(const half8*)(Kb + (size_t)(k0 + j) * DK + u2 * 8);
      const half8 h1 = *(const half8*)(Kb + (size_t)(k0 + j) * DK + u2 * 8 + 8);
      *(half8*)&Ks[(j * 8 + (u2 ^ (j & 7))) * 8] = h0;
      *(half8*)&Ks[(j * 8 + ((u2 + 1) ^ (j & 7))) * 8] = h1;
    }
    {  // V^T chunk via 4x4 register transpose
      const int kg = (t >> 4) * 4, dg = (t & 15) * 4;
      half4v f[4];
#pragma unroll
      for (int e = 0; e < 4; ++e)
        f[e] = *(const half4v*)(Vb + (size_t)(k0 + kg + e) * DK + dg);
#pragma unroll
      for (int i = 0; i < 4; ++i) {
        half4v hv = {f[0][i], f[1][i], f[2][i], f[3][i]};
        *(half4v*)&Vt[(dg + i) * 72 + kg] = hv;
      }
    }
    if constexpr (PREBIAS) {  // bias chunk: 2 coalesced f16x8 loads/thread
#pragma unroll
      for (int i = 0; i < 2; ++i) {
        const int u2 = t * 2 + i;
        const int row = u2 >> 3, seg = u2 & 7;
        const half8 hv = *(const half8*)(bbase + (size_t)row * SS + k0 + seg * 8);
        *(half8*)&biasL[row * 72 + seg * 8] = hv;
      }
    } else {  // inline geom bias (fallback)
      const int gq = t >> 2, gk = (t & 3) * 16;
#pragma unroll
      for (int sg = 0; sg < 4; ++sg) {
        float4 gv[7];
#pragma unroll
        for (int i7 = 0; i7 < 7; ++i7) gv[i7] = *(const float4*)(gptr + sg * 28 + i7 * 4);
        const float* gf = (const float*)gv;
        half4v bv;
#pragma unroll
        for (int k2 = 0; k2 < 4; ++k2) {
          float bi = bgh;
#pragma unroll
          for (int g = 0; g < GD; ++g) bi = fmaf(gf[k2 * GD + g], wgv[g], bi);
          bv[k2] = mskL[k0 + gk + sg * 4 + k2] ? (_Float16)bi : (_Float16)(-100.f);
        }
        *(half4v*)&biasL[gq * 72 + gk + sg * 4] = bv;
      }
      gptr += 64 * GD;
    }
    __syncthreads();

    // ---- QK^T: 8 MFMAs -> C-layout [q=quad*4+reg][key=nt*16+col] ----
    floatx4 sc[4] = {zero4, zero4, zero4, zero4};
#pragma unroll
    for (int nt = 0; nt < 4; ++nt) {
      const int key = nt * 16 + col;
#pragma unroll
      for (int kk = 0; kk < 2; ++kk) {
        const int u = quad + kk * 4;
        const half8 kf = *(const half8*)&Ks[(key * 8 + (u ^ (key & 7))) * 8];
        sc[nt] = __builtin_amdgcn_mfma_f32_16x16x32_f16(qfrag[kk], kf, sc[nt], 0, 0, 0);
      }
    }

    // ---- p = exp(s/8 + bias); masked keys have bias=-100 -> p==0 ----
#pragma unroll
    for (int nt = 0; nt < 4; ++nt) {
#pragma unroll
      for (int reg = 0; reg < 4; ++reg) {
        const int q = quad * 4 + reg;
        const float s =
            fmaf(sc[nt][reg], 0.125f, (float)biasL[(w * 16 + q) * 72 + nt * 16 + col]);
        const float p = __expf(s);
        lsum[reg] += p;
        pW[q * 72 + nt * 16 + col] = (_Float16)p;
      }
    }

    // ---- PV: 8 MFMAs ----
#pragma unroll
    for (int kk = 0; kk < 2; ++kk) {
      const half8 pa = *(const half8*)&pW[col * 72 + quad * 8 + kk * 32];
#pragma unroll
      for (int nt = 0; nt < 4; ++nt) {
        const half8 vb = *(const half8*)&Vt[(nt * 16 + col) * 72 + quad * 8 + kk * 32];
        ctx[nt] = __builtin_amdgcn_mfma_f32_16x16x32_f16(pa, vb, ctx[nt], 0, 0, 0);
      }
    }
  }

  float inv[4];
#pragma unroll
  for (int reg = 0; reg < 4; ++reg) {
    float l = lsum[reg];
    l += __shfl_xor(l, 1, 64);
    l += __shfl_xor(l, 2, 64);
    l += __shfl_xor(l, 4, 64);
    l += __shfl_xor(l, 8, 64);
    inv[reg] = 1.f / l;
  }
#pragma unroll
  for (int nt = 0; nt < 4; ++nt) {
#pragma unroll
    for (int reg = 0; reg < 4; ++reg) {
      const int q = q0 + w * 16 + quad * 4 + reg;
      ctxbuf[((size_t)b * SS + q) * DD + h * DK + nt * 16 + col] =
          (_Float16)(ctx[nt][reg] * inv[reg]);
    }
  }
}

// ---------------------------------------------------------------------------
extern "C" void kernel_launch(void* const* d_in, const int* in_sizes, int n_in,
                              void* d_out, int out_size, void* d_ws, size_t ws_size,
                              hipStream_t stream) {
  const float* x    = (const float*)d_in[0];
  const float* geom = (const float*)d_in[1];
  const int*   mask = (const int*)d_in[2];
  const float* Wq   = (const float*)d_in[3];
  const float* bq   = (const float*)d_in[4];
  const float* Wk   = (const float*)d_in[5];
  const float* bk   = (const float*)d_in[6];
  const float* Wv   = (const float*)d_in[7];
  const float* bv   = (const float*)d_in[8];
  const float* Wo   = (const float*)d_in[9];
  const float* bo   = (const float*)d_in[10];
  const float* Wg   = (const float*)d_in[11];
  const float* bg   = (const float*)d_in[12];
  float* out = (float*)d_out;

  const size_t NEL = (size_t)BB * SS * DD;  // 4,194,304
  char* p = (char*)d_ws;
  _Float16* xh   = (_Float16*)p;            p += NEL * 2;       // 8 MiB
  _Float16* Wt   = (_Float16*)p;            p += NEL * 2;       // 8 MiB (4x 1024x1024)
  _Float16* Qh   = (_Float16*)p;            p += NEL * 2;
  _Float16* Kh   = (_Float16*)p;            p += NEL * 2;
  _Float16* Vh   = (_Float16*)p;            p += NEL * 2;
  _Float16* ctxh = (_Float16*)p;            p += NEL * 2;       // 48 MiB total base
  _Float16* bias16 = (_Float16*)p;                               // +128 MiB
  const size_t need = (size_t)48 * 1024 * 1024 + (size_t)BB * NH * SS * SS * 2;
  const bool prebias = ws_size >= need;

  cvtx<<<2048, 256, 0, stream>>>(x, xh);
  packw<<<dim3(16, 16, 4), 256, 0, stream>>>(Wq, Wk, Wv, Wo, Wt);
  if (prebias)
    biasprep<<<dim3(SS, BB), 256, 0, stream>>>(geom, mask, Wg, bg, bias16);

  hgemm<0><<<dim3(32, 24), 256, 0, stream>>>(xh, Wt, bq, bk, bv, Qh, Kh, Vh, nullptr);

  if (prebias)
    attn<true><<<dim3(NH, SS / 64, BB), 256, 0, stream>>>(Qh, Kh, Vh, bias16, geom, mask,
                                                          Wg, bg, ctxh);
  else
    attn<false><<<dim3(NH, SS / 64, BB), 256, 0, stream>>>(Qh, Kh, Vh, nullptr, geom, mask,
                                                           Wg, bg, ctxh);

  hgemm<1><<<dim3(32, 8), 256, 0, stream>>>(ctxh, Wt + (size_t)3 * DD * DD, bo, nullptr,
                                            nullptr, nullptr, nullptr, nullptr, out);
}

// Round 5
// 369.116 us; speedup vs baseline: 3.8798x; 1.6792x over previous
//
#include <hip/hip_runtime.h>
#include <hip/hip_bf16.h>
#include <math.h>

// Problem constants (StructureGuidedAttention: B=4, S=1024, D=1024, H=16, dk=64, G=7)
#define BB 4
#define SS 1024
#define DD 1024
#define NH 16
#define DK 64
#define GD 7

typedef _Float16 half8 __attribute__((ext_vector_type(8)));
typedef _Float16 half4v __attribute__((ext_vector_type(4)));
typedef float floatx4 __attribute__((ext_vector_type(4)));

__device__ inline half8 cvt8(const float4 a, const float4 b) {
  half8 h;
  h[0] = (_Float16)a.x; h[1] = (_Float16)a.y; h[2] = (_Float16)a.z; h[3] = (_Float16)a.w;
  h[4] = (_Float16)b.x; h[5] = (_Float16)b.y; h[6] = (_Float16)b.z; h[7] = (_Float16)b.w;
  return h;
}

// ---------------------------------------------------------------------------
// x (fp32, 4M elements) -> f16
// ---------------------------------------------------------------------------
__global__ __launch_bounds__(256) void cvtx(const float* __restrict__ x,
                                            _Float16* __restrict__ xh) {
  const int i = blockIdx.x * 256 + threadIdx.x;
  const float4 a = ((const float4*)x)[i * 2];
  const float4 b = ((const float4*)x)[i * 2 + 1];
  ((half8*)xh)[i] = cvt8(a, b);
}

// ---------------------------------------------------------------------------
// Pack Wq|Wk|Wv|Wo (each [1024 k][1024 n] fp32) transposed into
// Wt[which][n][k] f16.  64x64 LDS tile transpose per block.
// ---------------------------------------------------------------------------
__global__ __launch_bounds__(256) void packw(const float* __restrict__ Wq,
                                             const float* __restrict__ Wk,
                                             const float* __restrict__ Wv,
                                             const float* __restrict__ Wo,
                                             _Float16* __restrict__ Wt) {
  __shared__ _Float16 Tl[64 * 72];  // [n][k] pitch 72 (16B-aligned rows)
  const int t = threadIdx.x;
  const int k0 = blockIdx.x * 64, n0 = blockIdx.y * 64, z = blockIdx.z;
  const float* src = (z == 0) ? Wq : (z == 1) ? Wk : (z == 2) ? Wv : Wo;
#pragma unroll
  for (int i = 0; i < 4; ++i) {
    const int u = i * 256 + t;
    const int r = u >> 4, c4 = (u & 15) * 4;  // k row r, n cols c4..c4+3
    const float4 v = *(const float4*)(src + (size_t)(k0 + r) * DD + n0 + c4);
    Tl[(c4 + 0) * 72 + r] = (_Float16)v.x;
    Tl[(c4 + 1) * 72 + r] = (_Float16)v.y;
    Tl[(c4 + 2) * 72 + r] = (_Float16)v.z;
    Tl[(c4 + 3) * 72 + r] = (_Float16)v.w;
  }
  __syncthreads();
  _Float16* dst = Wt + (size_t)z * DD * DD;
#pragma unroll
  for (int i = 0; i < 2; ++i) {
    const int u = i * 256 + t;
    const int nr = u >> 3, ks = u & 7;
    const half8 hv = *(const half8*)&Tl[nr * 72 + ks * 8];
    *(half8*)(dst + (size_t)(n0 + nr) * DD + k0 + ks * 8) = hv;
  }
}

// ---------------------------------------------------------------------------
// bias16[b][h][q][k] (f16) = geom[b,q,k,:] @ Wg[:,h] + bg[h]; -100 if masked.
// Block = (q, b). Thread t owns 4 consecutive keys: its 28 geom floats live
// in registers; it computes ALL 16 heads from them (no LDS for geom at all —
// the R4 version's geomL reads had address stride 448 floats = 16-way bank
// conflicts, 1.74e8 SQ_LDS_BANK_CONFLICT). Wg/bg staged in LDS, read as
// wave-uniform broadcasts (conflict-free). Writes: 8B half4v per head,
// consecutive lanes -> coalesced.
// ---------------------------------------------------------------------------
__global__ __launch_bounds__(256) void biasprep(const float* __restrict__ geom,
                                                const int* __restrict__ mask,
                                                const float* __restrict__ Wg,
                                                const float* __restrict__ bg,
                                                _Float16* __restrict__ bias16) {
  __shared__ float wgL[GD * NH + NH];  // Wg (112) + bg (16)
  const int t = threadIdx.x;
  const int q = blockIdx.x, b = blockIdx.y;
  if (t < GD * NH) wgL[t] = Wg[t];
  if (t < NH) wgL[GD * NH + t] = bg[t];

  // 4 keys per thread: 28 contiguous floats into registers (7 x float4)
  const float* gp = geom + ((size_t)b * SS + q) * SS * GD + (size_t)t * 28;
  float4 gv[7];
#pragma unroll
  for (int i = 0; i < 7; ++i) gv[i] = *(const float4*)(gp + i * 4);
  const float* gf = (const float*)gv;

  const int4 m4 = *(const int4*)(mask + b * SS + t * 4);
  const int mk[4] = {m4.x, m4.y, m4.z, m4.w};

  __syncthreads();

  _Float16* dst = bias16 + ((size_t)b * NH * SS + q) * SS + t * 4;
#pragma unroll
  for (int h = 0; h < NH; ++h) {
    float wg[GD];
#pragma unroll
    for (int g = 0; g < GD; ++g) wg[g] = wgL[g * NH + h];  // broadcast reads
    const float bgh = wgL[GD * NH + h];
    half4v hv;
#pragma unroll
    for (int k2 = 0; k2 < 4; ++k2) {
      float bi = bgh;
#pragma unroll
      for (int g = 0; g < GD; ++g) bi = fmaf(gf[k2 * GD + g], wg[g], bi);
      hv[k2] = mk[k2] ? (_Float16)bi : (_Float16)(-100.f);
    }
    *(half4v*)(dst + (size_t)h * SS * SS) = hv;
  }
}

// ---------------------------------------------------------------------------
// f16 MFMA GEMM, 128x128 tile, BK=64, 4 waves in 2x2.
// MODE 0: C[4096][3072] = xh @ Wt(qkv)^T + b  -> scatter f16 head-major Q/K/V
// MODE 1: C[4096][1024] = ctxh @ Wt(o)^T + bo -> fp32 row-major d_out
// ---------------------------------------------------------------------------
template <int MODE>
__global__ __launch_bounds__(256) void hgemm(const _Float16* __restrict__ A,
                                             const _Float16* __restrict__ Bt,
                                             const float* __restrict__ b0,
                                             const float* __restrict__ b1,
                                             const float* __restrict__ b2,
                                             _Float16* __restrict__ Oq,
                                             _Float16* __restrict__ Ok,
                                             _Float16* __restrict__ Ov,
                                             float* __restrict__ Of) {
  __shared__ _Float16 Als[128 * 72];  // [m][k] rows of 64 f16, pitch 72
  __shared__ _Float16 Bls[128 * 72];  // [n][k]
  const int t = threadIdx.x;
  const int w = t >> 6, lane = t & 63, quad = lane >> 4, col = lane & 15;
  const int m0 = blockIdx.x * 128, n0 = blockIdx.y * 128;
  const int mw = (w >> 1) * 64, nw = (w & 1) * 64;
  const floatx4 zero4 = {0.f, 0.f, 0.f, 0.f};
  floatx4 acc[4][4];
#pragma unroll
  for (int i = 0; i < 4; ++i)
#pragma unroll
    for (int j = 0; j < 4; ++j) acc[i][j] = zero4;

  for (int k0 = 0; k0 < DD; k0 += 64) {
#pragma unroll
    for (int i = 0; i < 4; ++i) {  // A tile: 128 rows x 8 f16x8-units
      const int u = i * 256 + t;
      const int row = u >> 3, seg = u & 7;
      const half8 hv = *(const half8*)(A + (size_t)(m0 + row) * DD + k0 + seg * 8);
      *(half8*)&Als[row * 72 + seg * 8] = hv;
    }
#pragma unroll
    for (int i = 0; i < 4; ++i) {  // B tile
      const int u = i * 256 + t;
      const int row = u >> 3, seg = u & 7;
      const half8 hv = *(const half8*)(Bt + (size_t)(n0 + row) * DD + k0 + seg * 8);
      *(half8*)&Bls[row * 72 + seg * 8] = hv;
    }
    __syncthreads();
#pragma unroll
    for (int kk = 0; kk < 2; ++kk) {
      half8 af[4], bf[4];
      const int u = (quad + kk * 4) * 8;
#pragma unroll
      for (int i = 0; i < 4; ++i) af[i] = *(const half8*)&Als[(mw + i * 16 + col) * 72 + u];
#pragma unroll
      for (int j = 0; j < 4; ++j) bf[j] = *(const half8*)&Bls[(nw + j * 16 + col) * 72 + u];
#pragma unroll
      for (int i = 0; i < 4; ++i)
#pragma unroll
        for (int j = 0; j < 4; ++j)
          acc[i][j] = __builtin_amdgcn_mfma_f32_16x16x32_f16(af[i], bf[j], acc[i][j], 0, 0, 0);
    }
    __syncthreads();
  }

#pragma unroll
  for (int j = 0; j < 4; ++j) {
    const int n = n0 + nw + j * 16 + col;
    if (MODE == 0) {
      const int which = n >> 10, hd = n & 1023;
      const int h = hd >> 6, d = hd & 63;
      const float* bp = (which == 0) ? b0 : (which == 1) ? b1 : b2;
      const float bias = bp[hd];
      _Float16* ob = (which == 0) ? Oq : (which == 1) ? Ok : Ov;
#pragma unroll
      for (int i = 0; i < 4; ++i) {
#pragma unroll
        for (int reg = 0; reg < 4; ++reg) {
          const int m = m0 + mw + i * 16 + quad * 4 + reg;
          const int b = m >> 10, s = m & 1023;
          ob[(((size_t)b * NH + h) * SS + s) * DK + d] = (_Float16)(acc[i][j][reg] + bias);
        }
      }
    } else {
      const float bias = b0[n];
#pragma unroll
      for (int i = 0; i < 4; ++i) {
#pragma unroll
        for (int reg = 0; reg < 4; ++reg) {
          const int m = m0 + mw + i * 16 + quad * 4 + reg;
          Of[(size_t)m * DD + n] = acc[i][j][reg] + bias;
        }
      }
    }
  }
}

// ---------------------------------------------------------------------------
// MFMA flash attention, f16 Q/K/V inputs, f16 ctx output.
// PREBIAS: bias read from precomputed bias16 (mask folded as -100).
// !PREBIAS: geom bias computed inline (fallback when ws is small).
// ---------------------------------------------------------------------------
template <bool PREBIAS>
__global__ __launch_bounds__(256) void attn(const _Float16* __restrict__ Q,
                                            const _Float16* __restrict__ K,
                                            const _Float16* __restrict__ V,
                                            const _Float16* __restrict__ bias16,
                                            const float* __restrict__ geom,
                                            const int* __restrict__ mask,
                                            const float* __restrict__ Wg,
                                            const float* __restrict__ bg,
                                            _Float16* __restrict__ ctxbuf) {
  __shared__ _Float16 Ks[64 * 64];      // K chunk, half8 XOR-swizzled (Q staging pre-loop)
  __shared__ _Float16 Vt[64 * 72];      // V^T chunk [dim][key], pitch 72
  __shared__ _Float16 biasL[64 * 72];   // bias chunk [q][key], pitch 72
  __shared__ _Float16 pL[4 * 16 * 72];  // per-wave P [16 q][key], pitch 72
  __shared__ unsigned char mskL[SS];    // fallback only

  const int t = threadIdx.x;
  const int w = t >> 6, lane = t & 63, quad = lane >> 4, col = lane & 15;
  const int h = blockIdx.x, qt = blockIdx.y, b = blockIdx.z;
  const int q0 = qt * 64;
  const size_t bh = (size_t)b * NH + h;
  const _Float16* Qb = Q + bh * SS * DK;
  const _Float16* Kb = K + bh * SS * DK;
  const _Float16* Vb = V + bh * SS * DK;

  {  // stage Q tile (64 q x 64 d) into Ks, swizzled
    const int j = t >> 2, u2 = (t & 3) * 2;
    const half8 h0 = *(const half8*)(Qb + (size_t)(q0 + j) * DK + u2 * 8);
    const half8 h1 = *(const half8*)(Qb + (size_t)(q0 + j) * DK + u2 * 8 + 8);
    *(half8*)&Ks[(j * 8 + (u2 ^ (j & 7))) * 8] = h0;
    *(half8*)&Ks[(j * 8 + ((u2 + 1) ^ (j & 7))) * 8] = h1;
  }
  if constexpr (!PREBIAS) {
    const int4 m4 = *(const int4*)(mask + b * SS + t * 4);
    mskL[t * 4 + 0] = m4.x != 0;
    mskL[t * 4 + 1] = m4.y != 0;
    mskL[t * 4 + 2] = m4.z != 0;
    mskL[t * 4 + 3] = m4.w != 0;
  }
  __syncthreads();
  half8 qfrag[2];
  {
    const int qrow = w * 16 + col;
#pragma unroll
    for (int kk = 0; kk < 2; ++kk) {
      const int u = quad + kk * 4;
      qfrag[kk] = *(const half8*)&Ks[(qrow * 8 + (u ^ (qrow & 7))) * 8];
    }
  }

  float wgv[GD];
  float bgh = 0.f;
  const float* gptr = nullptr;
  if constexpr (!PREBIAS) {
#pragma unroll
    for (int g = 0; g < GD; ++g) wgv[g] = Wg[g * NH + h];
    bgh = bg[h];
    gptr = geom + (((size_t)b * SS + (q0 + (t >> 2))) * SS + (t & 3) * 16) * GD;
  }
  const _Float16* bbase = nullptr;
  if constexpr (PREBIAS) bbase = bias16 + (bh * SS + q0) * SS;

  const floatx4 zero4 = {0.f, 0.f, 0.f, 0.f};
  floatx4 ctx[4] = {zero4, zero4, zero4, zero4};
  float lsum[4] = {0.f, 0.f, 0.f, 0.f};
  _Float16* pW = &pL[w * 16 * 72];

  for (int c = 0; c < 16; ++c) {
    const int k0 = c * 64;
    __syncthreads();  // prev-chunk consumers done (also protects qfrag at c==0)

    {  // K chunk, swizzled
      const int j = t >> 2, u2 = (t & 3) * 2;
      const half8 h0 = *(const half8*)(Kb + (size_t)(k0 + j) * DK + u2 * 8);
      const half8 h1 = *(const half8*)(Kb + (size_t)(k0 + j) * DK + u2 * 8 + 8);
      *(half8*)&Ks[(j * 8 + (u2 ^ (j & 7))) * 8] = h0;
      *(half8*)&Ks[(j * 8 + ((u2 + 1) ^ (j & 7))) * 8] = h1;
    }
    {  // V^T chunk via 4x4 register transpose
      const int kg = (t >> 4) * 4, dg = (t & 15) * 4;
      half4v f[4];
#pragma unroll
      for (int e = 0; e < 4; ++e)
        f[e] = *(const half4v*)(Vb + (size_t)(k0 + kg + e) * DK + dg);
#pragma unroll
      for (int i = 0; i < 4; ++i) {
        half4v hv = {f[0][i], f[1][i], f[2][i], f[3][i]};
        *(half4v*)&Vt[(dg + i) * 72 + kg] = hv;
      }
    }
    if constexpr (PREBIAS) {  // bias chunk: 2 coalesced f16x8 loads/thread
#pragma unroll
      for (int i = 0; i < 2; ++i) {
        const int u2 = t * 2 + i;
        const int row = u2 >> 3, seg = u2 & 7;
        const half8 hv = *(const half8*)(bbase + (size_t)row * SS + k0 + seg * 8);
        *(half8*)&biasL[row * 72 + seg * 8] = hv;
      }
    } else {  // inline geom bias (fallback)
      const int gq = t >> 2, gk = (t & 3) * 16;
#pragma unroll
      for (int sg = 0; sg < 4; ++sg) {
        float4 gv[7];
#pragma unroll
        for (int i7 = 0; i7 < 7; ++i7) gv[i7] = *(const float4*)(gptr + sg * 28 + i7 * 4);
        const float* gf = (const float*)gv;
        half4v bv;
#pragma unroll
        for (int k2 = 0; k2 < 4; ++k2) {
          float bi = bgh;
#pragma unroll
          for (int g = 0; g < GD; ++g) bi = fmaf(gf[k2 * GD + g], wgv[g], bi);
          bv[k2] = mskL[k0 + gk + sg * 4 + k2] ? (_Float16)bi : (_Float16)(-100.f);
        }
        *(half4v*)&biasL[gq * 72 + gk + sg * 4] = bv;
      }
      gptr += 64 * GD;
    }
    __syncthreads();

    // ---- QK^T: 8 MFMAs -> C-layout [q=quad*4+reg][key=nt*16+col] ----
    floatx4 sc[4] = {zero4, zero4, zero4, zero4};
#pragma unroll
    for (int nt = 0; nt < 4; ++nt) {
      const int key = nt * 16 + col;
#pragma unroll
      for (int kk = 0; kk < 2; ++kk) {
        const int u = quad + kk * 4;
        const half8 kf = *(const half8*)&Ks[(key * 8 + (u ^ (key & 7))) * 8];
        sc[nt] = __builtin_amdgcn_mfma_f32_16x16x32_f16(qfrag[kk], kf, sc[nt], 0, 0, 0);
      }
    }

    // ---- p = exp(s/8 + bias); masked keys have bias=-100 -> p==0 ----
#pragma unroll
    for (int nt = 0; nt < 4; ++nt) {
#pragma unroll
      for (int reg = 0; reg < 4; ++reg) {
        const int q = quad * 4 + reg;
        const float s =
            fmaf(sc[nt][reg], 0.125f, (float)biasL[(w * 16 + q) * 72 + nt * 16 + col]);
        const float p = __expf(s);
        lsum[reg] += p;
        pW[q * 72 + nt * 16 + col] = (_Float16)p;
      }
    }

    // ---- PV: 8 MFMAs ----
#pragma unroll
    for (int kk = 0; kk < 2; ++kk) {
      const half8 pa = *(const half8*)&pW[col * 72 + quad * 8 + kk * 32];
#pragma unroll
      for (int nt = 0; nt < 4; ++nt) {
        const half8 vb = *(const half8*)&Vt[(nt * 16 + col) * 72 + quad * 8 + kk * 32];
        ctx[nt] = __builtin_amdgcn_mfma_f32_16x16x32_f16(pa, vb, ctx[nt], 0, 0, 0);
      }
    }
  }

  float inv[4];
#pragma unroll
  for (int reg = 0; reg < 4; ++reg) {
    float l = lsum[reg];
    l += __shfl_xor(l, 1, 64);
    l += __shfl_xor(l, 2, 64);
    l += __shfl_xor(l, 4, 64);
    l += __shfl_xor(l, 8, 64);
    inv[reg] = 1.f / l;
  }
#pragma unroll
  for (int nt = 0; nt < 4; ++nt) {
#pragma unroll
    for (int reg = 0; reg < 4; ++reg) {
      const int q = q0 + w * 16 + quad * 4 + reg;
      ctxbuf[((size_t)b * SS + q) * DD + h * DK + nt * 16 + col] =
          (_Float16)(ctx[nt][reg] * inv[reg]);
    }
  }
}

// ---------------------------------------------------------------------------
extern "C" void kernel_launch(void* const* d_in, const int* in_sizes, int n_in,
                              void* d_out, int out_size, void* d_ws, size_t ws_size,
                              hipStream_t stream) {
  const float* x    = (const float*)d_in[0];
  const float* geom = (const float*)d_in[1];
  const int*   mask = (const int*)d_in[2];
  const float* Wq   = (const float*)d_in[3];
  const float* bq   = (const float*)d_in[4];
  const float* Wk   = (const float*)d_in[5];
  const float* bk   = (const float*)d_in[6];
  const float* Wv   = (const float*)d_in[7];
  const float* bv   = (const float*)d_in[8];
  const float* Wo   = (const float*)d_in[9];
  const float* bo   = (const float*)d_in[10];
  const float* Wg   = (const float*)d_in[11];
  const float* bg   = (const float*)d_in[12];
  float* out = (float*)d_out;

  const size_t NEL = (size_t)BB * SS * DD;  // 4,194,304
  char* p = (char*)d_ws;
  _Float16* xh   = (_Float16*)p;            p += NEL * 2;       // 8 MiB
  _Float16* Wt   = (_Float16*)p;            p += NEL * 2;       // 8 MiB (4x 1024x1024)
  _Float16* Qh   = (_Float16*)p;            p += NEL * 2;
  _Float16* Kh   = (_Float16*)p;            p += NEL * 2;
  _Float16* Vh   = (_Float16*)p;            p += NEL * 2;
  _Float16* ctxh = (_Float16*)p;            p += NEL * 2;       // 48 MiB total base
  _Float16* bias16 = (_Float16*)p;                               // +128 MiB
  const size_t need = (size_t)48 * 1024 * 1024 + (size_t)BB * NH * SS * SS * 2;
  const bool prebias = ws_size >= need;

  cvtx<<<2048, 256, 0, stream>>>(x, xh);
  packw<<<dim3(16, 16, 4), 256, 0, stream>>>(Wq, Wk, Wv, Wo, Wt);
  if (prebias)
    biasprep<<<dim3(SS, BB), 256, 0, stream>>>(geom, mask, Wg, bg, bias16);

  hgemm<0><<<dim3(32, 24), 256, 0, stream>>>(xh, Wt, bq, bk, bv, Qh, Kh, Vh, nullptr);

  if (prebias)
    attn<true><<<dim3(NH, SS / 64, BB), 256, 0, stream>>>(Qh, Kh, Vh, bias16, geom, mask,
                                                          Wg, bg, ctxh);
  else
    attn<false><<<dim3(NH, SS / 64, BB), 256, 0, stream>>>(Qh, Kh, Vh, nullptr, geom, mask,
                                                           Wg, bg, ctxh);

  hgemm<1><<<dim3(32, 8), 256, 0, stream>>>(ctxh, Wt + (size_t)3 * DD * DD, bo, nullptr,
                                            nullptr, nullptr, nullptr, nullptr, out);
}

// Round 6
// 363.248 us; speedup vs baseline: 3.9425x; 1.0162x over previous
//
#include <hip/hip_runtime.h>
#include <hip/hip_bf16.h>
#include <math.h>

// Problem constants (StructureGuidedAttention: B=4, S=1024, D=1024, H=16, dk=64, G=7)
#define BB 4
#define SS 1024
#define DD 1024
#define NH 16
#define DK 64
#define GD 7

typedef _Float16 half8 __attribute__((ext_vector_type(8)));
typedef _Float16 half4v __attribute__((ext_vector_type(4)));
typedef float floatx4 __attribute__((ext_vector_type(4)));

__device__ inline half8 cvt8(const float4 a, const float4 b) {
  half8 h;
  h[0] = (_Float16)a.x; h[1] = (_Float16)a.y; h[2] = (_Float16)a.z; h[3] = (_Float16)a.w;
  h[4] = (_Float16)b.x; h[5] = (_Float16)b.y; h[6] = (_Float16)b.z; h[7] = (_Float16)b.w;
  return h;
}

// ---------------------------------------------------------------------------
// prep: blocks 0..2047 = x fp32 -> f16; blocks 2048..3071 = pack W^T f16.
// (The two jobs are independent; merged to share one dispatch.)
// ---------------------------------------------------------------------------
__global__ __launch_bounds__(256) void prep(const float* __restrict__ x,
                                            _Float16* __restrict__ xh,
                                            const float* __restrict__ Wq,
                                            const float* __restrict__ Wk,
                                            const float* __restrict__ Wv,
                                            const float* __restrict__ Wo,
                                            _Float16* __restrict__ Wt) {
  __shared__ _Float16 Tl[64 * 72];  // packw transpose tile [n][k], pitch 72
  const int t = threadIdx.x;
  if (blockIdx.x < 2048) {  // ---- cvtx ----
    const int i = blockIdx.x * 256 + t;
    const float4 a = ((const float4*)x)[i * 2];
    const float4 b = ((const float4*)x)[i * 2 + 1];
    ((half8*)xh)[i] = cvt8(a, b);
    return;
  }
  // ---- packw: 64x64 LDS tile transpose ----
  const int pf = blockIdx.x - 2048;
  const int z = pf >> 8, rem = pf & 255;
  const int n0 = (rem >> 4) * 64, k0 = (rem & 15) * 64;
  const float* src = (z == 0) ? Wq : (z == 1) ? Wk : (z == 2) ? Wv : Wo;
#pragma unroll
  for (int i = 0; i < 4; ++i) {
    const int u = i * 256 + t;
    const int r = u >> 4, c4 = (u & 15) * 4;  // k row r, n cols c4..c4+3
    const float4 v = *(const float4*)(src + (size_t)(k0 + r) * DD + n0 + c4);
    Tl[(c4 + 0) * 72 + r] = (_Float16)v.x;
    Tl[(c4 + 1) * 72 + r] = (_Float16)v.y;
    Tl[(c4 + 2) * 72 + r] = (_Float16)v.z;
    Tl[(c4 + 3) * 72 + r] = (_Float16)v.w;
  }
  __syncthreads();
  _Float16* dst = Wt + (size_t)z * DD * DD;
#pragma unroll
  for (int i = 0; i < 2; ++i) {
    const int u = i * 256 + t;
    const int nr = u >> 3, ks = u & 7;
    const half8 hv = *(const half8*)&Tl[nr * 72 + ks * 8];
    *(half8*)(dst + (size_t)(n0 + nr) * DD + k0 + ks * 8) = hv;
  }
}

// ---------------------------------------------------------------------------
// fused0: blocks 0..767 = QKV hgemm (128x128 tile, f16 MFMA);
//         blocks 768+   = biasprep (8 keys/thread, half8 stores).
// The two jobs use disjoint pipes (MFMA vs HBM) and have no dependency —
// merged so the HW co-schedules them (m114: overlap = max, not sum).
// ---------------------------------------------------------------------------
template <bool PRE>
__global__ __launch_bounds__(256) void fused0(const _Float16* __restrict__ A,
                                              const _Float16* __restrict__ Bt,
                                              const float* __restrict__ bq,
                                              const float* __restrict__ bk,
                                              const float* __restrict__ bv,
                                              _Float16* __restrict__ Oq,
                                              _Float16* __restrict__ Ok,
                                              _Float16* __restrict__ Ov,
                                              const float* __restrict__ geom,
                                              const int* __restrict__ mask,
                                              const float* __restrict__ Wg,
                                              const float* __restrict__ bg,
                                              _Float16* __restrict__ bias16) {
  const int t = threadIdx.x;
  if (blockIdx.x < 768) {
    // ================= QKV GEMM =================
    __shared__ _Float16 Als[128 * 72];  // [m][k], pitch 72 (2-way-free b128 reads)
    __shared__ _Float16 Bls[128 * 72];  // [n][k]
    const int w = t >> 6, lane = t & 63, quad = lane >> 4, col = lane & 15;
    const int m0 = (blockIdx.x & 31) * 128, n0 = (blockIdx.x >> 5) * 128;
    const int mw = (w >> 1) * 64, nw = (w & 1) * 64;
    const floatx4 zero4 = {0.f, 0.f, 0.f, 0.f};
    floatx4 acc[4][4];
#pragma unroll
    for (int i = 0; i < 4; ++i)
#pragma unroll
      for (int j = 0; j < 4; ++j) acc[i][j] = zero4;

    for (int k0 = 0; k0 < DD; k0 += 64) {
#pragma unroll
      for (int i = 0; i < 4; ++i) {  // A tile: 128 rows x 8 f16x8-units
        const int u = i * 256 + t;
        const int row = u >> 3, seg = u & 7;
        const half8 hv = *(const half8*)(A + (size_t)(m0 + row) * DD + k0 + seg * 8);
        *(half8*)&Als[row * 72 + seg * 8] = hv;
      }
#pragma unroll
      for (int i = 0; i < 4; ++i) {  // B tile
        const int u = i * 256 + t;
        const int row = u >> 3, seg = u & 7;
        const half8 hv = *(const half8*)(Bt + (size_t)(n0 + row) * DD + k0 + seg * 8);
        *(half8*)&Bls[row * 72 + seg * 8] = hv;
      }
      __syncthreads();
#pragma unroll
      for (int kk = 0; kk < 2; ++kk) {
        half8 af[4], bf[4];
        const int u = (quad + kk * 4) * 8;
#pragma unroll
        for (int i = 0; i < 4; ++i)
          af[i] = *(const half8*)&Als[(mw + i * 16 + col) * 72 + u];
#pragma unroll
        for (int j = 0; j < 4; ++j)
          bf[j] = *(const half8*)&Bls[(nw + j * 16 + col) * 72 + u];
#pragma unroll
        for (int i = 0; i < 4; ++i)
#pragma unroll
          for (int j = 0; j < 4; ++j)
            acc[i][j] =
                __builtin_amdgcn_mfma_f32_16x16x32_f16(af[i], bf[j], acc[i][j], 0, 0, 0);
      }
      __syncthreads();
    }

#pragma unroll
    for (int j = 0; j < 4; ++j) {
      const int n = n0 + nw + j * 16 + col;
      const int which = n >> 10, hd = n & 1023;
      const int h = hd >> 6, d = hd & 63;
      const float* bp = (which == 0) ? bq : (which == 1) ? bk : bv;
      const float bias = bp[hd];
      _Float16* ob = (which == 0) ? Oq : (which == 1) ? Ok : Ov;
#pragma unroll
      for (int i = 0; i < 4; ++i) {
#pragma unroll
        for (int reg = 0; reg < 4; ++reg) {
          const int m = m0 + mw + i * 16 + quad * 4 + reg;
          const int b = m >> 10, s = m & 1023;
          ob[(((size_t)b * NH + h) * SS + s) * DK + d] = (_Float16)(acc[i][j][reg] + bias);
        }
      }
    }
    return;
  }

  if constexpr (PRE) {
    // ================= biasprep: 8 keys/thread, all 16 heads =================
    __shared__ float wgL[GD * NH + NH];
    const int r = blockIdx.x - 768;           // 0..2047
    const int b = r >> 9;                     // 0..3
    const int q = (r & 511) * 2 + (t >> 7);   // 2 q-rows per block
    const int k8 = (t & 127) * 8;             // 8 consecutive keys
    if (t < GD * NH) wgL[t] = Wg[t];
    if (t < NH) wgL[GD * NH + t] = bg[t];

    const float* gp = geom + ((size_t)b * SS + q) * SS * GD + (size_t)k8 * GD;
    float4 gv[14];  // 8 keys x 7 features = 56 floats
#pragma unroll
    for (int i = 0; i < 14; ++i) gv[i] = *(const float4*)(gp + i * 4);
    const float* gf = (const float*)gv;

    const int4 m4a = *(const int4*)(mask + b * SS + k8);
    const int4 m4b = *(const int4*)(mask + b * SS + k8 + 4);
    const int mk[8] = {m4a.x, m4a.y, m4a.z, m4a.w, m4b.x, m4b.y, m4b.z, m4b.w};

    __syncthreads();

    _Float16* dst = bias16 + ((size_t)b * NH * SS + q) * SS + k8;
#pragma unroll
    for (int h = 0; h < NH; ++h) {
      float wg[GD];
#pragma unroll
      for (int g = 0; g < GD; ++g) wg[g] = wgL[g * NH + h];  // broadcast reads
      const float bgh = wgL[GD * NH + h];
      half8 hv;
#pragma unroll
      for (int k2 = 0; k2 < 8; ++k2) {
        float bi = bgh;
#pragma unroll
        for (int g = 0; g < GD; ++g) bi = fmaf(gf[k2 * GD + g], wg[g], bi);
        hv[k2] = mk[k2] ? (_Float16)bi : (_Float16)(-100.f);
      }
      *(half8*)(dst + (size_t)h * SS * SS) = hv;
    }
  }
}

// ---------------------------------------------------------------------------
// Out-projection hgemm: C[4096][1024] = ctxh @ Wt(o)^T + bo -> fp32 d_out
// ---------------------------------------------------------------------------
__global__ __launch_bounds__(256) void hgemm1(const _Float16* __restrict__ A,
                                              const _Float16* __restrict__ Bt,
                                              const float* __restrict__ b0,
                                              float* __restrict__ Of) {
  __shared__ _Float16 Als[128 * 72];
  __shared__ _Float16 Bls[128 * 72];
  const int t = threadIdx.x;
  const int w = t >> 6, lane = t & 63, quad = lane >> 4, col = lane & 15;
  const int m0 = blockIdx.x * 128, n0 = blockIdx.y * 128;
  const int mw = (w >> 1) * 64, nw = (w & 1) * 64;
  const floatx4 zero4 = {0.f, 0.f, 0.f, 0.f};
  floatx4 acc[4][4];
#pragma unroll
  for (int i = 0; i < 4; ++i)
#pragma unroll
    for (int j = 0; j < 4; ++j) acc[i][j] = zero4;

  for (int k0 = 0; k0 < DD; k0 += 64) {
#pragma unroll
    for (int i = 0; i < 4; ++i) {
      const int u = i * 256 + t;
      const int row = u >> 3, seg = u & 7;
      const half8 hv = *(const half8*)(A + (size_t)(m0 + row) * DD + k0 + seg * 8);
      *(half8*)&Als[row * 72 + seg * 8] = hv;
    }
#pragma unroll
    for (int i = 0; i < 4; ++i) {
      const int u = i * 256 + t;
      const int row = u >> 3, seg = u & 7;
      const half8 hv = *(const half8*)(Bt + (size_t)(n0 + row) * DD + k0 + seg * 8);
      *(half8*)&Bls[row * 72 + seg * 8] = hv;
    }
    __syncthreads();
#pragma unroll
    for (int kk = 0; kk < 2; ++kk) {
      half8 af[4], bf[4];
      const int u = (quad + kk * 4) * 8;
#pragma unroll
      for (int i = 0; i < 4; ++i) af[i] = *(const half8*)&Als[(mw + i * 16 + col) * 72 + u];
#pragma unroll
      for (int j = 0; j < 4; ++j) bf[j] = *(const half8*)&Bls[(nw + j * 16 + col) * 72 + u];
#pragma unroll
      for (int i = 0; i < 4; ++i)
#pragma unroll
        for (int j = 0; j < 4; ++j)
          acc[i][j] = __builtin_amdgcn_mfma_f32_16x16x32_f16(af[i], bf[j], acc[i][j], 0, 0, 0);
    }
    __syncthreads();
  }

#pragma unroll
  for (int j = 0; j < 4; ++j) {
    const int n = n0 + nw + j * 16 + col;
    const float bias = b0[n];
#pragma unroll
    for (int i = 0; i < 4; ++i) {
#pragma unroll
      for (int reg = 0; reg < 4; ++reg) {
        const int m = m0 + mw + i * 16 + quad * 4 + reg;
        Of[(size_t)m * DD + n] = acc[i][j][reg] + bias;
      }
    }
  }
}

// ---------------------------------------------------------------------------
// MFMA flash attention, f16 Q/K/V inputs, f16 ctx output.
// PREBIAS: bias read from precomputed bias16 (mask folded as -100).
// !PREBIAS: geom bias computed inline (fallback when ws is small).
// ---------------------------------------------------------------------------
template <bool PREBIAS>
__global__ __launch_bounds__(256) void attn(const _Float16* __restrict__ Q,
                                            const _Float16* __restrict__ K,
                                            const _Float16* __restrict__ V,
                                            const _Float16* __restrict__ bias16,
                                            const float* __restrict__ geom,
                                            const int* __restrict__ mask,
                                            const float* __restrict__ Wg,
                                            const float* __restrict__ bg,
                                            _Float16* __restrict__ ctxbuf) {
  __shared__ _Float16 Ks[64 * 64];      // K chunk, half8 XOR-swizzled (Q staging pre-loop)
  __shared__ _Float16 Vt[64 * 72];      // V^T chunk [dim][key], pitch 72
  __shared__ _Float16 biasL[64 * 72];   // bias chunk [q][key], pitch 72
  __shared__ _Float16 pL[4 * 16 * 72];  // per-wave P [16 q][key], pitch 72
  __shared__ unsigned char mskL[SS];    // fallback only

  const int t = threadIdx.x;
  const int w = t >> 6, lane = t & 63, quad = lane >> 4, col = lane & 15;
  const int h = blockIdx.x, qt = blockIdx.y, b = blockIdx.z;
  const int q0 = qt * 64;
  const size_t bh = (size_t)b * NH + h;
  const _Float16* Qb = Q + bh * SS * DK;
  const _Float16* Kb = K + bh * SS * DK;
  const _Float16* Vb = V + bh * SS * DK;

  {  // stage Q tile (64 q x 64 d) into Ks, swizzled
    const int j = t >> 2, u2 = (t & 3) * 2;
    const half8 h0 = *(const half8*)(Qb + (size_t)(q0 + j) * DK + u2 * 8);
    const half8 h1 = *(const half8*)(Qb + (size_t)(q0 + j) * DK + u2 * 8 + 8);
    *(half8*)&Ks[(j * 8 + (u2 ^ (j & 7))) * 8] = h0;
    *(half8*)&Ks[(j * 8 + ((u2 + 1) ^ (j & 7))) * 8] = h1;
  }
  if constexpr (!PREBIAS) {
    const int4 m4 = *(const int4*)(mask + b * SS + t * 4);
    mskL[t * 4 + 0] = m4.x != 0;
    mskL[t * 4 + 1] = m4.y != 0;
    mskL[t * 4 + 2] = m4.z != 0;
    mskL[t * 4 + 3] = m4.w != 0;
  }
  __syncthreads();
  half8 qfrag[2];
  {
    const int qrow = w * 16 + col;
#pragma unroll
    for (int kk = 0; kk < 2; ++kk) {
      const int u = quad + kk * 4;
      qfrag[kk] = *(const half8*)&Ks[(qrow * 8 + (u ^ (qrow & 7))) * 8];
    }
  }

  float wgv[GD];
  float bgh = 0.f;
  const float* gptr = nullptr;
  if constexpr (!PREBIAS) {
#pragma unroll
    for (int g = 0; g < GD; ++g) wgv[g] = Wg[g * NH + h];
    bgh = bg[h];
    gptr = geom + (((size_t)b * SS + (q0 + (t >> 2))) * SS + (t & 3) * 16) * GD;
  }
  const _Float16* bbase = nullptr;
  if constexpr (PREBIAS) bbase = bias16 + (bh * SS + q0) * SS;

  const floatx4 zero4 = {0.f, 0.f, 0.f, 0.f};
  floatx4 ctx[4] = {zero4, zero4, zero4, zero4};
  float lsum[4] = {0.f, 0.f, 0.f, 0.f};
  _Float16* pW = &pL[w * 16 * 72];

  for (int c = 0; c < 16; ++c) {
    const int k0 = c * 64;
    __syncthreads();  // prev-chunk consumers done (also protects qfrag at c==0)

    {  // K chunk, swizzled
      const int j = t >> 2, u2 = (t & 3) * 2;
      const half8 h0 = *(const half8*)(Kb + (size_t)(k0 + j) * DK + u2 * 8);
      const half8 h1 = *(const half8*)(Kb + (size_t)(k0 + j) * DK + u2 * 8 + 8);
      *(half8*)&Ks[(j * 8 + (u2 ^ (j & 7))) * 8] = h0;
      *(half8*)&Ks[(j * 8 + ((u2 + 1) ^ (j & 7))) * 8] = h1;
    }
    {  // V^T chunk via 4x4 register transpose
      const int kg = (t >> 4) * 4, dg = (t & 15) * 4;
      half4v f[4];
#pragma unroll
      for (int e = 0; e < 4; ++e)
        f[e] = *(const half4v*)(Vb + (size_t)(k0 + kg + e) * DK + dg);
#pragma unroll
      for (int i = 0; i < 4; ++i) {
        half4v hv = {f[0][i], f[1][i], f[2][i], f[3][i]};
        *(half4v*)&Vt[(dg + i) * 72 + kg] = hv;
      }
    }
    if constexpr (PREBIAS) {  // bias chunk: 2 coalesced f16x8 loads/thread
#pragma unroll
      for (int i = 0; i < 2; ++i) {
        const int u2 = t * 2 + i;
        const int row = u2 >> 3, seg = u2 & 7;
        const half8 hv = *(const half8*)(bbase + (size_t)row * SS + k0 + seg * 8);
        *(half8*)&biasL[row * 72 + seg * 8] = hv;
      }
    } else {  // inline geom bias (fallback)
      const int gq = t >> 2, gk = (t & 3) * 16;
#pragma unroll
      for (int sg = 0; sg < 4; ++sg) {
        float4 gv[7];
#pragma unroll
        for (int i7 = 0; i7 < 7; ++i7) gv[i7] = *(const float4*)(gptr + sg * 28 + i7 * 4);
        const float* gf = (const float*)gv;
        half4v bv;
#pragma unroll
        for (int k2 = 0; k2 < 4; ++k2) {
          float bi = bgh;
#pragma unroll
          for (int g = 0; g < GD; ++g) bi = fmaf(gf[k2 * GD + g], wgv[g], bi);
          bv[k2] = mskL[k0 + gk + sg * 4 + k2] ? (_Float16)bi : (_Float16)(-100.f);
        }
        *(half4v*)&biasL[gq * 72 + gk + sg * 4] = bv;
      }
      gptr += 64 * GD;
    }
    __syncthreads();

    // ---- QK^T: 8 MFMAs -> C-layout [q=quad*4+reg][key=nt*16+col] ----
    floatx4 sc[4] = {zero4, zero4, zero4, zero4};
#pragma unroll
    for (int nt = 0; nt < 4; ++nt) {
      const int key = nt * 16 + col;
#pragma unroll
      for (int kk = 0; kk < 2; ++kk) {
        const int u = quad + kk * 4;
        const half8 kf = *(const half8*)&Ks[(key * 8 + (u ^ (key & 7))) * 8];
        sc[nt] = __builtin_amdgcn_mfma_f32_16x16x32_f16(qfrag[kk], kf, sc[nt], 0, 0, 0);
      }
    }

    // ---- p = exp(s/8 + bias); masked keys have bias=-100 -> p==0 ----
#pragma unroll
    for (int nt = 0; nt < 4; ++nt) {
#pragma unroll
      for (int reg = 0; reg < 4; ++reg) {
        const int q = quad * 4 + reg;
        const float s =
            fmaf(sc[nt][reg], 0.125f, (float)biasL[(w * 16 + q) * 72 + nt * 16 + col]);
        const float p = __expf(s);
        lsum[reg] += p;
        pW[q * 72 + nt * 16 + col] = (_Float16)p;
      }
    }

    // ---- PV: 8 MFMAs ----
#pragma unroll
    for (int kk = 0; kk < 2; ++kk) {
      const half8 pa = *(const half8*)&pW[col * 72 + quad * 8 + kk * 32];
#pragma unroll
      for (int nt = 0; nt < 4; ++nt) {
        const half8 vb = *(const half8*)&Vt[(nt * 16 + col) * 72 + quad * 8 + kk * 32];
        ctx[nt] = __builtin_amdgcn_mfma_f32_16x16x32_f16(pa, vb, ctx[nt], 0, 0, 0);
      }
    }
  }

  float inv[4];
#pragma unroll
  for (int reg = 0; reg < 4; ++reg) {
    float l = lsum[reg];
    l += __shfl_xor(l, 1, 64);
    l += __shfl_xor(l, 2, 64);
    l += __shfl_xor(l, 4, 64);
    l += __shfl_xor(l, 8, 64);
    inv[reg] = 1.f / l;
  }
#pragma unroll
  for (int nt = 0; nt < 4; ++nt) {
#pragma unroll
    for (int reg = 0; reg < 4; ++reg) {
      const int q = q0 + w * 16 + quad * 4 + reg;
      ctxbuf[((size_t)b * SS + q) * DD + h * DK + nt * 16 + col] =
          (_Float16)(ctx[nt][reg] * inv[reg]);
    }
  }
}

// ---------------------------------------------------------------------------
extern "C" void kernel_launch(void* const* d_in, const int* in_sizes, int n_in,
                              void* d_out, int out_size, void* d_ws, size_t ws_size,
                              hipStream_t stream) {
  const float* x    = (const float*)d_in[0];
  const float* geom = (const float*)d_in[1];
  const int*   mask = (const int*)d_in[2];
  const float* Wq   = (const float*)d_in[3];
  const float* bq   = (const float*)d_in[4];
  const float* Wk   = (const float*)d_in[5];
  const float* bk   = (const float*)d_in[6];
  const float* Wv   = (const float*)d_in[7];
  const float* bv   = (const float*)d_in[8];
  const float* Wo   = (const float*)d_in[9];
  const float* bo   = (const float*)d_in[10];
  const float* Wg   = (const float*)d_in[11];
  const float* bg   = (const float*)d_in[12];
  float* out = (float*)d_out;

  const size_t NEL = (size_t)BB * SS * DD;  // 4,194,304
  char* p = (char*)d_ws;
  _Float16* xh   = (_Float16*)p;            p += NEL * 2;       // 8 MiB
  _Float16* Wt   = (_Float16*)p;            p += NEL * 2;       // 8 MiB (4x 1024x1024)
  _Float16* Qh   = (_Float16*)p;            p += NEL * 2;
  _Float16* Kh   = (_Float16*)p;            p += NEL * 2;
  _Float16* Vh   = (_Float16*)p;            p += NEL * 2;
  _Float16* ctxh = (_Float16*)p;            p += NEL * 2;       // 48 MiB total base
  _Float16* bias16 = (_Float16*)p;                               // +128 MiB
  const size_t need = (size_t)48 * 1024 * 1024 + (size_t)BB * NH * SS * SS * 2;
  const bool prebias = ws_size >= need;

  prep<<<3072, 256, 0, stream>>>(x, xh, Wq, Wk, Wv, Wo, Wt);

  if (prebias) {
    fused0<true><<<768 + 2048, 256, 0, stream>>>(xh, Wt, bq, bk, bv, Qh, Kh, Vh,
                                                 geom, mask, Wg, bg, bias16);
    attn<true><<<dim3(NH, SS / 64, BB), 256, 0, stream>>>(Qh, Kh, Vh, bias16, geom, mask,
                                                          Wg, bg, ctxh);
  } else {
    fused0<false><<<768, 256, 0, stream>>>(xh, Wt, bq, bk, bv, Qh, Kh, Vh,
                                           geom, mask, Wg, bg, nullptr);
    attn<false><<<dim3(NH, SS / 64, BB), 256, 0, stream>>>(Qh, Kh, Vh, nullptr, geom, mask,
                                                           Wg, bg, ctxh);
  }

  hgemm1<<<dim3(32, 8), 256, 0, stream>>>(ctxh, Wt + (size_t)3 * DD * DD, bo, out);
}

// Round 7
// 337.793 us; speedup vs baseline: 4.2395x; 1.0754x over previous
//
#include <hip/hip_runtime.h>
#include <hip/hip_bf16.h>
#include <math.h>

// Problem constants (StructureGuidedAttention: B=4, S=1024, D=1024, H=16, dk=64, G=7)
#define BB 4
#define SS 1024
#define DD 1024
#define NH 16
#define DK 64
#define GD 7

typedef _Float16 half8 __attribute__((ext_vector_type(8)));
typedef _Float16 half4v __attribute__((ext_vector_type(4)));
typedef float floatx4 __attribute__((ext_vector_type(4)));

__device__ inline half8 cvt8(const float4 a, const float4 b) {
  half8 h;
  h[0] = (_Float16)a.x; h[1] = (_Float16)a.y; h[2] = (_Float16)a.z; h[3] = (_Float16)a.w;
  h[4] = (_Float16)b.x; h[5] = (_Float16)b.y; h[6] = (_Float16)b.z; h[7] = (_Float16)b.w;
  return h;
}

// ---------------------------------------------------------------------------
// prep: blocks 0..2047 = x fp32 -> f16; blocks 2048..3071 = pack W^T f16.
// ---------------------------------------------------------------------------
__global__ __launch_bounds__(256) void prep(const float* __restrict__ x,
                                            _Float16* __restrict__ xh,
                                            const float* __restrict__ Wq,
                                            const float* __restrict__ Wk,
                                            const float* __restrict__ Wv,
                                            const float* __restrict__ Wo,
                                            _Float16* __restrict__ Wt) {
  __shared__ _Float16 Tl[64 * 72];  // packw transpose tile [n][k], pitch 72
  const int t = threadIdx.x;
  if (blockIdx.x < 2048) {  // ---- cvtx ----
    const int i = blockIdx.x * 256 + t;
    const float4 a = ((const float4*)x)[i * 2];
    const float4 b = ((const float4*)x)[i * 2 + 1];
    ((half8*)xh)[i] = cvt8(a, b);
    return;
  }
  // ---- packw: 64x64 LDS tile transpose ----
  const int pf = blockIdx.x - 2048;
  const int z = pf >> 8, rem = pf & 255;
  const int n0 = (rem >> 4) * 64, k0 = (rem & 15) * 64;
  const float* src = (z == 0) ? Wq : (z == 1) ? Wk : (z == 2) ? Wv : Wo;
#pragma unroll
  for (int i = 0; i < 4; ++i) {
    const int u = i * 256 + t;
    const int r = u >> 4, c4 = (u & 15) * 4;
    const float4 v = *(const float4*)(src + (size_t)(k0 + r) * DD + n0 + c4);
    Tl[(c4 + 0) * 72 + r] = (_Float16)v.x;
    Tl[(c4 + 1) * 72 + r] = (_Float16)v.y;
    Tl[(c4 + 2) * 72 + r] = (_Float16)v.z;
    Tl[(c4 + 3) * 72 + r] = (_Float16)v.w;
  }
  __syncthreads();
  _Float16* dst = Wt + (size_t)z * DD * DD;
#pragma unroll
  for (int i = 0; i < 2; ++i) {
    const int u = i * 256 + t;
    const int nr = u >> 3, ks = u & 7;
    const half8 hv = *(const half8*)&Tl[nr * 72 + ks * 8];
    *(half8*)(dst + (size_t)(n0 + nr) * DD + k0 + ks * 8) = hv;
  }
}

// ---------------------------------------------------------------------------
// fused0: QKV hgemm (768 virtual blocks) + biasprep->fp8 (2048 virtual blocks),
// role-INTERLEAVED 3:8 over 2816 = 11*256 blocks so every CU runs a
// GEMM:biasprep mix from t=0 (R6's 0..767-then-768.. ordering only overlapped
// mid-dispatch). bias stored as fp8 e4m3 (values tiny, std~0.05; -100 mask
// -> -96 -> exp = 0 still) halving bias HBM traffic.
// ---------------------------------------------------------------------------
template <bool PRE>
__global__ __launch_bounds__(256) void fused0(const _Float16* __restrict__ A,
                                              const _Float16* __restrict__ Bt,
                                              const float* __restrict__ bq,
                                              const float* __restrict__ bk,
                                              const float* __restrict__ bv,
                                              _Float16* __restrict__ Oq,
                                              _Float16* __restrict__ Ok,
                                              _Float16* __restrict__ Ov,
                                              const float* __restrict__ geom,
                                              const int* __restrict__ mask,
                                              const float* __restrict__ Wg,
                                              const float* __restrict__ bg,
                                              unsigned char* __restrict__ bias8) {
  const int t = threadIdx.x;
  int role, idx;
  if (PRE) {
    const int g = blockIdx.x, grp = g / 11, rem = g % 11;  // 2816 = 11*256, 768:2048 = 3:8
    if (rem < 3) { role = 0; idx = grp * 3 + rem; }
    else         { role = 1; idx = grp * 8 + rem - 3; }
  } else {
    role = 0; idx = blockIdx.x;
  }

  if (role == 0) {
    // ================= QKV GEMM =================
    __shared__ _Float16 Als[128 * 72];  // [m][k], pitch 72
    __shared__ _Float16 Bls[128 * 72];  // [n][k]
    const int w = t >> 6, lane = t & 63, quad = lane >> 4, col = lane & 15;
    const int m0 = (idx & 31) * 128, n0 = (idx >> 5) * 128;
    const int mw = (w >> 1) * 64, nw = (w & 1) * 64;
    const floatx4 zero4 = {0.f, 0.f, 0.f, 0.f};
    floatx4 acc[4][4];
#pragma unroll
    for (int i = 0; i < 4; ++i)
#pragma unroll
      for (int j = 0; j < 4; ++j) acc[i][j] = zero4;

    for (int k0 = 0; k0 < DD; k0 += 64) {
#pragma unroll
      for (int i = 0; i < 4; ++i) {
        const int u = i * 256 + t;
        const int row = u >> 3, seg = u & 7;
        const half8 hv = *(const half8*)(A + (size_t)(m0 + row) * DD + k0 + seg * 8);
        *(half8*)&Als[row * 72 + seg * 8] = hv;
      }
#pragma unroll
      for (int i = 0; i < 4; ++i) {
        const int u = i * 256 + t;
        const int row = u >> 3, seg = u & 7;
        const half8 hv = *(const half8*)(Bt + (size_t)(n0 + row) * DD + k0 + seg * 8);
        *(half8*)&Bls[row * 72 + seg * 8] = hv;
      }
      __syncthreads();
#pragma unroll
      for (int kk = 0; kk < 2; ++kk) {
        half8 af[4], bf[4];
        const int u = (quad + kk * 4) * 8;
#pragma unroll
        for (int i = 0; i < 4; ++i)
          af[i] = *(const half8*)&Als[(mw + i * 16 + col) * 72 + u];
#pragma unroll
        for (int j = 0; j < 4; ++j)
          bf[j] = *(const half8*)&Bls[(nw + j * 16 + col) * 72 + u];
#pragma unroll
        for (int i = 0; i < 4; ++i)
#pragma unroll
          for (int j = 0; j < 4; ++j)
            acc[i][j] =
                __builtin_amdgcn_mfma_f32_16x16x32_f16(af[i], bf[j], acc[i][j], 0, 0, 0);
      }
      __syncthreads();
    }

#pragma unroll
    for (int j = 0; j < 4; ++j) {
      const int n = n0 + nw + j * 16 + col;
      const int which = n >> 10, hd = n & 1023;
      const int h = hd >> 6, d = hd & 63;
      const float* bp = (which == 0) ? bq : (which == 1) ? bk : bv;
      const float bias = bp[hd];
      _Float16* ob = (which == 0) ? Oq : (which == 1) ? Ok : Ov;
#pragma unroll
      for (int i = 0; i < 4; ++i) {
#pragma unroll
        for (int reg = 0; reg < 4; ++reg) {
          const int m = m0 + mw + i * 16 + quad * 4 + reg;
          const int b = m >> 10, s = m & 1023;
          ob[(((size_t)b * NH + h) * SS + s) * DK + d] = (_Float16)(acc[i][j][reg] + bias);
        }
      }
    }
    return;
  }

  if constexpr (PRE) {
    // ============ biasprep: 8 keys/thread, 16 heads, fp8 output ============
    __shared__ float wgL[GD * NH + NH];
    const int r = idx;                        // 0..2047
    const int b = r >> 9;                     // 0..3
    const int q = (r & 511) * 2 + (t >> 7);   // 2 q-rows per block
    const int k8 = (t & 127) * 8;             // 8 consecutive keys
    if (t < GD * NH) wgL[t] = Wg[t];
    if (t < NH) wgL[GD * NH + t] = bg[t];

    const float* gp = geom + ((size_t)b * SS + q) * SS * GD + (size_t)k8 * GD;
    float4 gv[14];  // 8 keys x 7 features
#pragma unroll
    for (int i = 0; i < 14; ++i) gv[i] = *(const float4*)(gp + i * 4);
    const float* gf = (const float*)gv;

    const int4 m4a = *(const int4*)(mask + b * SS + k8);
    const int4 m4b = *(const int4*)(mask + b * SS + k8 + 4);
    const int mk[8] = {m4a.x, m4a.y, m4a.z, m4a.w, m4b.x, m4b.y, m4b.z, m4b.w};

    __syncthreads();

    unsigned char* dst = bias8 + ((size_t)b * NH * SS + q) * SS + k8;
#pragma unroll
    for (int h = 0; h < NH; ++h) {
      float wg[GD];
#pragma unroll
      for (int g = 0; g < GD; ++g) wg[g] = wgL[g * NH + h];  // broadcast reads
      const float bgh = wgL[GD * NH + h];
      float bi[8];
#pragma unroll
      for (int k2 = 0; k2 < 8; ++k2) {
        float s = bgh;
#pragma unroll
        for (int g = 0; g < GD; ++g) s = fmaf(gf[k2 * GD + g], wg[g], s);
        bi[k2] = mk[k2] ? s : -100.f;
      }
      // pack 8 floats -> 8 fp8 e4m3 (HW cvt_pk)
      int w0 = 0, w1 = 0;
      w0 = __builtin_amdgcn_cvt_pk_fp8_f32(bi[0], bi[1], w0, false);
      w0 = __builtin_amdgcn_cvt_pk_fp8_f32(bi[2], bi[3], w0, true);
      w1 = __builtin_amdgcn_cvt_pk_fp8_f32(bi[4], bi[5], w1, false);
      w1 = __builtin_amdgcn_cvt_pk_fp8_f32(bi[6], bi[7], w1, true);
      uint2 u2v;
      u2v.x = (unsigned)w0;
      u2v.y = (unsigned)w1;
      *(uint2*)(dst + (size_t)h * SS * SS) = u2v;
    }
  }
}

// ---------------------------------------------------------------------------
// Out-projection hgemm: C[4096][1024] = ctxh @ Wt(o)^T + bo -> fp32 d_out
// ---------------------------------------------------------------------------
__global__ __launch_bounds__(256) void hgemm1(const _Float16* __restrict__ A,
                                              const _Float16* __restrict__ Bt,
                                              const float* __restrict__ b0,
                                              float* __restrict__ Of) {
  __shared__ _Float16 Als[128 * 72];
  __shared__ _Float16 Bls[128 * 72];
  const int t = threadIdx.x;
  const int w = t >> 6, lane = t & 63, quad = lane >> 4, col = lane & 15;
  const int m0 = blockIdx.x * 128, n0 = blockIdx.y * 128;
  const int mw = (w >> 1) * 64, nw = (w & 1) * 64;
  const floatx4 zero4 = {0.f, 0.f, 0.f, 0.f};
  floatx4 acc[4][4];
#pragma unroll
  for (int i = 0; i < 4; ++i)
#pragma unroll
    for (int j = 0; j < 4; ++j) acc[i][j] = zero4;

  for (int k0 = 0; k0 < DD; k0 += 64) {
#pragma unroll
    for (int i = 0; i < 4; ++i) {
      const int u = i * 256 + t;
      const int row = u >> 3, seg = u & 7;
      const half8 hv = *(const half8*)(A + (size_t)(m0 + row) * DD + k0 + seg * 8);
      *(half8*)&Als[row * 72 + seg * 8] = hv;
    }
#pragma unroll
    for (int i = 0; i < 4; ++i) {
      const int u = i * 256 + t;
      const int row = u >> 3, seg = u & 7;
      const half8 hv = *(const half8*)(Bt + (size_t)(n0 + row) * DD + k0 + seg * 8);
      *(half8*)&Bls[row * 72 + seg * 8] = hv;
    }
    __syncthreads();
#pragma unroll
    for (int kk = 0; kk < 2; ++kk) {
      half8 af[4], bf[4];
      const int u = (quad + kk * 4) * 8;
#pragma unroll
      for (int i = 0; i < 4; ++i) af[i] = *(const half8*)&Als[(mw + i * 16 + col) * 72 + u];
#pragma unroll
      for (int j = 0; j < 4; ++j) bf[j] = *(const half8*)&Bls[(nw + j * 16 + col) * 72 + u];
#pragma unroll
      for (int i = 0; i < 4; ++i)
#pragma unroll
        for (int j = 0; j < 4; ++j)
          acc[i][j] = __builtin_amdgcn_mfma_f32_16x16x32_f16(af[i], bf[j], acc[i][j], 0, 0, 0);
    }
    __syncthreads();
  }

#pragma unroll
  for (int j = 0; j < 4; ++j) {
    const int n = n0 + nw + j * 16 + col;
    const float bias = b0[n];
#pragma unroll
    for (int i = 0; i < 4; ++i) {
#pragma unroll
      for (int reg = 0; reg < 4; ++reg) {
        const int m = m0 + mw + i * 16 + quad * 4 + reg;
        Of[(size_t)m * DD + n] = acc[i][j][reg] + bias;
      }
    }
  }
}

// ---------------------------------------------------------------------------
// MFMA flash attention, f16 Q/K/V, f16 ctx out.
// PREBIAS: bias8 (fp8 e4m3) chunk staged to LDS (pitch 80B), cvt_f32_fp8 at use.
// !PREBIAS: inline geom bias fallback (f16 biasL, pitch 72 elements).
// ---------------------------------------------------------------------------
template <bool PREBIAS>
__global__ __launch_bounds__(256) void attn(const _Float16* __restrict__ Q,
                                            const _Float16* __restrict__ K,
                                            const _Float16* __restrict__ V,
                                            const unsigned char* __restrict__ bias8,
                                            const float* __restrict__ geom,
                                            const int* __restrict__ mask,
                                            const float* __restrict__ Wg,
                                            const float* __restrict__ bg,
                                            _Float16* __restrict__ ctxbuf) {
  __shared__ _Float16 Ks[64 * 64];      // K chunk, half8 XOR-swizzled (Q staging pre-loop)
  __shared__ _Float16 Vt[64 * 72];      // V^T chunk [dim][key], pitch 72
  __shared__ unsigned char biasL[PREBIAS ? 64 * 80 : 64 * 144];  // fp8 pitch-80B | f16 pitch-72el
  __shared__ _Float16 pL[4 * 16 * 72];  // per-wave P [16 q][key], pitch 72
  __shared__ unsigned char mskL[SS];    // fallback only

  const int t = threadIdx.x;
  const int w = t >> 6, lane = t & 63, quad = lane >> 4, col = lane & 15;
  const int h = blockIdx.x, qt = blockIdx.y, b = blockIdx.z;
  const int q0 = qt * 64;
  const size_t bh = (size_t)b * NH + h;
  const _Float16* Qb = Q + bh * SS * DK;
  const _Float16* Kb = K + bh * SS * DK;
  const _Float16* Vb = V + bh * SS * DK;
  _Float16* biasLf = (_Float16*)biasL;

  {  // stage Q tile into Ks, swizzled
    const int j = t >> 2, u2 = (t & 3) * 2;
    const half8 h0 = *(const half8*)(Qb + (size_t)(q0 + j) * DK + u2 * 8);
    const half8 h1 = *(const half8*)(Qb + (size_t)(q0 + j) * DK + u2 * 8 + 8);
    *(half8*)&Ks[(j * 8 + (u2 ^ (j & 7))) * 8] = h0;
    *(half8*)&Ks[(j * 8 + ((u2 + 1) ^ (j & 7))) * 8] = h1;
  }
  if constexpr (!PREBIAS) {
    const int4 m4 = *(const int4*)(mask + b * SS + t * 4);
    mskL[t * 4 + 0] = m4.x != 0;
    mskL[t * 4 + 1] = m4.y != 0;
    mskL[t * 4 + 2] = m4.z != 0;
    mskL[t * 4 + 3] = m4.w != 0;
  }
  __syncthreads();
  half8 qfrag[2];
  {
    const int qrow = w * 16 + col;
#pragma unroll
    for (int kk = 0; kk < 2; ++kk) {
      const int u = quad + kk * 4;
      qfrag[kk] = *(const half8*)&Ks[(qrow * 8 + (u ^ (qrow & 7))) * 8];
    }
  }

  float wgv[GD];
  float bgh = 0.f;
  const float* gptr = nullptr;
  if constexpr (!PREBIAS) {
#pragma unroll
    for (int g = 0; g < GD; ++g) wgv[g] = Wg[g * NH + h];
    bgh = bg[h];
    gptr = geom + (((size_t)b * SS + (q0 + (t >> 2))) * SS + (t & 3) * 16) * GD;
  }
  const unsigned char* bb8 = nullptr;
  if constexpr (PREBIAS) bb8 = bias8 + (bh * SS + q0) * SS;

  const floatx4 zero4 = {0.f, 0.f, 0.f, 0.f};
  floatx4 ctx[4] = {zero4, zero4, zero4, zero4};
  float lsum[4] = {0.f, 0.f, 0.f, 0.f};
  _Float16* pW = &pL[w * 16 * 72];

  for (int c = 0; c < 16; ++c) {
    const int k0 = c * 64;
    __syncthreads();

    {  // K chunk, swizzled
      const int j = t >> 2, u2 = (t & 3) * 2;
      const half8 h0 = *(const half8*)(Kb + (size_t)(k0 + j) * DK + u2 * 8);
      const half8 h1 = *(const half8*)(Kb + (size_t)(k0 + j) * DK + u2 * 8 + 8);
      *(half8*)&Ks[(j * 8 + (u2 ^ (j & 7))) * 8] = h0;
      *(half8*)&Ks[(j * 8 + ((u2 + 1) ^ (j & 7))) * 8] = h1;
    }
    {  // V^T chunk via 4x4 register transpose
      const int kg = (t >> 4) * 4, dg = (t & 15) * 4;
      half4v f[4];
#pragma unroll
      for (int e = 0; e < 4; ++e)
        f[e] = *(const half4v*)(Vb + (size_t)(k0 + kg + e) * DK + dg);
#pragma unroll
      for (int i = 0; i < 4; ++i) {
        half4v hv = {f[0][i], f[1][i], f[2][i], f[3][i]};
        *(half4v*)&Vt[(dg + i) * 72 + kg] = hv;
      }
    }
    if constexpr (PREBIAS) {  // fp8 bias chunk: one uint4 (16 keys) per thread
      const int row = t >> 2, seg = (t & 3) * 16;
      const uint4 v = *(const uint4*)(bb8 + (size_t)row * SS + k0 + seg);
      *(uint4*)&biasL[row * 80 + seg] = v;
    } else {  // inline geom bias (fallback)
      const int gq = t >> 2, gk = (t & 3) * 16;
#pragma unroll
      for (int sg = 0; sg < 4; ++sg) {
        float4 gvv[7];
#pragma unroll
        for (int i7 = 0; i7 < 7; ++i7) gvv[i7] = *(const float4*)(gptr + sg * 28 + i7 * 4);
        const float* gf = (const float*)gvv;
        half4v bv;
#pragma unroll
        for (int k2 = 0; k2 < 4; ++k2) {
          float bi = bgh;
#pragma unroll
          for (int g = 0; g < GD; ++g) bi = fmaf(gf[k2 * GD + g], wgv[g], bi);
          bv[k2] = mskL[k0 + gk + sg * 4 + k2] ? (_Float16)bi : (_Float16)(-100.f);
        }
        *(half4v*)&biasLf[gq * 72 + gk + sg * 4] = bv;
      }
      gptr += 64 * GD;
    }
    __syncthreads();

    // ---- QK^T: 8 MFMAs -> C-layout [q=quad*4+reg][key=nt*16+col] ----
    floatx4 sc[4] = {zero4, zero4, zero4, zero4};
#pragma unroll
    for (int nt = 0; nt < 4; ++nt) {
      const int key = nt * 16 + col;
#pragma unroll
      for (int kk = 0; kk < 2; ++kk) {
        const int u = quad + kk * 4;
        const half8 kf = *(const half8*)&Ks[(key * 8 + (u ^ (key & 7))) * 8];
        sc[nt] = __builtin_amdgcn_mfma_f32_16x16x32_f16(qfrag[kk], kf, sc[nt], 0, 0, 0);
      }
    }

    // ---- p = exp(s/8 + bias); masked keys carry bias=-100 -> p==0 ----
#pragma unroll
    for (int nt = 0; nt < 4; ++nt) {
#pragma unroll
      for (int reg = 0; reg < 4; ++reg) {
        const int q = quad * 4 + reg;
        float bias;
        if constexpr (PREBIAS) {
          bias = __builtin_amdgcn_cvt_f32_fp8(
              (int)biasL[(w * 16 + q) * 80 + nt * 16 + col], 0);
        } else {
          bias = (float)biasLf[(w * 16 + q) * 72 + nt * 16 + col];
        }
        const float s = fmaf(sc[nt][reg], 0.125f, bias);
        const float p = __expf(s);
        lsum[reg] += p;
        pW[q * 72 + nt * 16 + col] = (_Float16)p;
      }
    }

    // ---- PV: 8 MFMAs ----
#pragma unroll
    for (int kk = 0; kk < 2; ++kk) {
      const half8 pa = *(const half8*)&pW[col * 72 + quad * 8 + kk * 32];
#pragma unroll
      for (int nt = 0; nt < 4; ++nt) {
        const half8 vb = *(const half8*)&Vt[(nt * 16 + col) * 72 + quad * 8 + kk * 32];
        ctx[nt] = __builtin_amdgcn_mfma_f32_16x16x32_f16(pa, vb, ctx[nt], 0, 0, 0);
      }
    }
  }

  float inv[4];
#pragma unroll
  for (int reg = 0; reg < 4; ++reg) {
    float l = lsum[reg];
    l += __shfl_xor(l, 1, 64);
    l += __shfl_xor(l, 2, 64);
    l += __shfl_xor(l, 4, 64);
    l += __shfl_xor(l, 8, 64);
    inv[reg] = 1.f / l;
  }
#pragma unroll
  for (int nt = 0; nt < 4; ++nt) {
#pragma unroll
    for (int reg = 0; reg < 4; ++reg) {
      const int q = q0 + w * 16 + quad * 4 + reg;
      ctxbuf[((size_t)b * SS + q) * DD + h * DK + nt * 16 + col] =
          (_Float16)(ctx[nt][reg] * inv[reg]);
    }
  }
}

// ---------------------------------------------------------------------------
extern "C" void kernel_launch(void* const* d_in, const int* in_sizes, int n_in,
                              void* d_out, int out_size, void* d_ws, size_t ws_size,
                              hipStream_t stream) {
  const float* x    = (const float*)d_in[0];
  const float* geom = (const float*)d_in[1];
  const int*   mask = (const int*)d_in[2];
  const float* Wq   = (const float*)d_in[3];
  const float* bq   = (const float*)d_in[4];
  const float* Wk   = (const float*)d_in[5];
  const float* bk   = (const float*)d_in[6];
  const float* Wv   = (const float*)d_in[7];
  const float* bv   = (const float*)d_in[8];
  const float* Wo   = (const float*)d_in[9];
  const float* bo   = (const float*)d_in[10];
  const float* Wg   = (const float*)d_in[11];
  const float* bg   = (const float*)d_in[12];
  float* out = (float*)d_out;

  const size_t NEL = (size_t)BB * SS * DD;  // 4,194,304
  char* p = (char*)d_ws;
  _Float16* xh   = (_Float16*)p;            p += NEL * 2;
  _Float16* Wt   = (_Float16*)p;            p += NEL * 2;
  _Float16* Qh   = (_Float16*)p;            p += NEL * 2;
  _Float16* Kh   = (_Float16*)p;            p += NEL * 2;
  _Float16* Vh   = (_Float16*)p;            p += NEL * 2;
  _Float16* ctxh = (_Float16*)p;            p += NEL * 2;       // 48 MiB base
  unsigned char* bias8 = (unsigned char*)p;                     // +64 MiB (fp8)
  const size_t need = (size_t)48 * 1024 * 1024 + (size_t)BB * NH * SS * SS;
  const bool prebias = ws_size >= need;

  prep<<<3072, 256, 0, stream>>>(x, xh, Wq, Wk, Wv, Wo, Wt);

  if (prebias) {
    fused0<true><<<2816, 256, 0, stream>>>(xh, Wt, bq, bk, bv, Qh, Kh, Vh,
                                           geom, mask, Wg, bg, bias8);
    attn<true><<<dim3(NH, SS / 64, BB), 256, 0, stream>>>(Qh, Kh, Vh, bias8, geom, mask,
                                                          Wg, bg, ctxh);
  } else {
    fused0<false><<<768, 256, 0, stream>>>(xh, Wt, bq, bk, bv, Qh, Kh, Vh,
                                           geom, mask, Wg, bg, nullptr);
    attn<false><<<dim3(NH, SS / 64, BB), 256, 0, stream>>>(Qh, Kh, Vh, nullptr, geom, mask,
                                                           Wg, bg, ctxh);
  }

  hgemm1<<<dim3(32, 8), 256, 0, stream>>>(ctxh, Wt + (size_t)3 * DD * DD, bo, out);
}